// Round 1
// baseline (2195.248 us; speedup 1.0000x reference)
//
#include <hip/hip_runtime.h>
#include <hip/hip_bf16.h>
#include <math.h>

// Problem constants (fixed by reference)
#define NNODES 8191      // tree nodes, ids 0..8190 (topological: children < parent)
#define ROOT   8190
#define NROWS  8192      // tree nodes + appended focal row
#define FOCALR 8191
#define NLEAF  4096
#define HID    512
#define EDIM   2050

// Output layout (fp32 elements, concat in return order)
#define OUT_LOGITS 0
#define OUT_PROBS  8191
#define OUT_EF     16382
#define OUT_EMB    16807932   // 16382 + 8191*2050
#define OUT_FOCAL  21002236   // + 8192*512

__device__ __forceinline__ float4 ld4(const float* p) { return *(const float4*)p; }
__device__ __forceinline__ void st4(float* p, float4 v) { *(float4*)p = v; }

// ---------------- focal one-hot output ----------------
__global__ void focal_kernel(const int* __restrict__ cfl, float* __restrict__ outf) {
    int i = blockIdx.x * 256 + threadIdx.x;
    if (i < NLEAF) outf[i] = (i == cfl[0]) ? 1.0f : 0.0f;
}

// ---------------- postorder: c[u] and y_post rows (512-d projected belief prop) ---------
// y_post[leaf] is implicit: row ns[leaf] of W1. Internal: y_post[u]=cu*(row(ch0)+row(ch1)).
// Readiness flag for internal node a: c[a] > 0 (published with agent release; cu in [1/3,0.5]).
__global__ __launch_bounds__(256) void post_kernel(const int* __restrict__ ns,
                                                   const int* __restrict__ ch0,
                                                   const int* __restrict__ ch1,
                                                   const float* __restrict__ W1,
                                                   float* c, float* __restrict__ ypost) {
    int gtid = blockIdx.x * 256 + threadIdx.x;
    int wave = gtid >> 6, lane = gtid & 63;
    const int nw = 1024;  // 256 blocks * 4 waves, all co-resident on 256 CUs
    for (int u = wave; u < NNODES; u += nw) {
        if (ns[u] >= 0) continue;  // leaf: nothing to do
        int a = ch0[u], b = ch1[u];
        bool la = (ns[a] >= 0), lb = (ns[b] >= 0);
        float ca = 0.0f, cb = 0.0f;
        if (!la) while ((ca = __hip_atomic_load(&c[a], __ATOMIC_ACQUIRE, __HIP_MEMORY_SCOPE_AGENT)) <= 0.0f)
                     __builtin_amdgcn_s_sleep(1);
        if (!lb) while ((cb = __hip_atomic_load(&c[b], __ATOMIC_ACQUIRE, __HIP_MEMORY_SCOPE_AGENT)) <= 0.0f)
                     __builtin_amdgcn_s_sleep(1);
        float cu = 1.0f / (3.0f - ca - cb);
        const float* ra = la ? (W1 + (long)ns[a] * HID) : (ypost + (long)a * HID);
        const float* rb = lb ? (W1 + (long)ns[b] * HID) : (ypost + (long)b * HID);
        float* dst = ypost + (long)u * HID;
        for (int j = lane * 4; j < HID; j += 64 * 4) {
            float4 x = ld4(ra + j), yv = ld4(rb + j), r;
            r.x = cu * (x.x + yv.x); r.y = cu * (x.y + yv.y);
            r.z = cu * (x.z + yv.z); r.w = cu * (x.w + yv.w);
            st4(dst + j, r);
        }
        __threadfence();
        if (lane == 0) __hip_atomic_store(&c[u], cu, __ATOMIC_RELEASE, __HIP_MEMORY_SCOPE_AGENT);
    }
}

// ---------------- preorder: y[u] = y_post[u] + c[u]*y[parent]; leaves/focal = W1 rows ----
__global__ __launch_bounds__(256) void pre_kernel(const int* __restrict__ ns,
                                                  const int* __restrict__ par,
                                                  const int* __restrict__ cflp,
                                                  const float* __restrict__ W1,
                                                  const float* __restrict__ c,
                                                  const float* __restrict__ ypost,
                                                  float* __restrict__ y, float* flag2) {
    int gtid = blockIdx.x * 256 + threadIdx.x;
    int wave = gtid >> 6, lane = gtid & 63;
    const int nw = 1024;
    for (int u = (NROWS - 1) - wave; u >= 0; u -= nw) {
        float* dst = y + (long)u * HID;
        if (u == FOCALR) {  // focal row: one_hot(cfl) @ W1 = W1[cfl,:]
            const float* src = W1 + (long)cflp[0] * HID;
            for (int j = lane * 4; j < HID; j += 256) st4(dst + j, ld4(src + j));
            continue;  // nothing depends on this row's flag
        }
        if (ns[u] >= 0) {  // leaf: c=0, y = W1[ns[u],:]; no one polls leaves
            const float* src = W1 + (long)ns[u] * HID;
            for (int j = lane * 4; j < HID; j += 256) st4(dst + j, ld4(src + j));
            continue;
        }
        if (u == ROOT) {
            const float* src = ypost + (long)u * HID;
            for (int j = lane * 4; j < HID; j += 256) st4(dst + j, ld4(src + j));
        } else {
            int p = par[u];
            while (__hip_atomic_load(&flag2[p], __ATOMIC_ACQUIRE, __HIP_MEMORY_SCOPE_AGENT) != 1.0f)
                __builtin_amdgcn_s_sleep(1);
            float cu = c[u];
            const float* sp = ypost + (long)u * HID;
            const float* pp = y + (long)p * HID;
            for (int j = lane * 4; j < HID; j += 256) {
                float4 a = ld4(sp + j), b = ld4(pp + j), r;
                r.x = a.x + cu * b.x; r.y = a.y + cu * b.y;
                r.z = a.z + cu * b.z; r.w = a.w + cu * b.w;
                st4(dst + j, r);
            }
        }
        __threadfence();
        if (lane == 0) __hip_atomic_store(&flag2[u], 1.0f, __ATOMIC_RELEASE, __HIP_MEMORY_SCOPE_AGENT);
    }
}

// ---------------- GCN neighbor aggregation in 512-d (linearity of matmul) -------------
template <int RELU, int BIAS>
__global__ __launch_bounds__(128) void gcn_agg_kernel(const float* __restrict__ xin,
                                                      const int* __restrict__ neigh,
                                                      const float* __restrict__ bias,
                                                      float* __restrict__ xout) {
    int u = blockIdx.x;        // 0..8191
    int t = threadIdx.x;       // 128 threads * float4 = 512
    int n0 = neigh[u * 3 + 0], n1 = neigh[u * 3 + 1], n2 = neigh[u * 3 + 2];
    float deg = 1.0f + (n0 >= 0) + (n1 >= 0) + (n2 >= 0);
    float4 s = ld4(xin + (long)u * HID + t * 4);
    if (n0 >= 0) { float4 v = ld4(xin + (long)n0 * HID + t * 4); s.x += v.x; s.y += v.y; s.z += v.z; s.w += v.w; }
    if (n1 >= 0) { float4 v = ld4(xin + (long)n1 * HID + t * 4); s.x += v.x; s.y += v.y; s.z += v.z; s.w += v.w; }
    if (n2 >= 0) { float4 v = ld4(xin + (long)n2 * HID + t * 4); s.x += v.x; s.y += v.y; s.z += v.z; s.w += v.w; }
    float inv = 1.0f / deg;
    s.x *= inv; s.y *= inv; s.z *= inv; s.w *= inv;
    if (BIAS) { float4 b = ld4(bias + t * 4); s.x += b.x; s.y += b.y; s.z += b.z; s.w += b.w; }
    if (RELU) { s.x = fmaxf(s.x, 0.f); s.y = fmaxf(s.y, 0.f); s.z = fmaxf(s.z, 0.f); s.w = fmaxf(s.w, 0.f); }
    st4(xout + (long)u * HID + t * 4, s);
}

// ---------------- generic fp32 GEMM: C = act(A@W + bias), A:MxK (lda), W:KxN, C (ldc) ---
// ACT: 0 none, 1 relu, 2 elu
template <int ACT>
__global__ __launch_bounds__(256) void gemm_kernel(const float* __restrict__ A,
                                                   const float* __restrict__ W,
                                                   const float* __restrict__ bias,
                                                   float* __restrict__ C,
                                                   int M, int N, int K, int lda, int ldc) {
    __shared__ float As[16][65];  // [k][m], padded
    __shared__ float Ws[16][65];  // [k][n], padded
    int bx = blockIdx.x, by = blockIdx.y;
    int tid = threadIdx.x;
    int tx = tid % 16, ty = tid / 16;
    int row0 = by * 64 + ty * 4;
    int col0 = bx * 64 + tx * 4;
    float acc[4][4] = {};
    for (int k0 = 0; k0 < K; k0 += 16) {
#pragma unroll
        for (int j = 0; j < 4; j++) {
            int idx = tid * 4 + j;
            int m = idx >> 4, kk = idx & 15;
            int gr = by * 64 + m, gk = k0 + kk;
            As[kk][m] = (gr < M && gk < K) ? A[(long)gr * lda + gk] : 0.0f;
        }
#pragma unroll
        for (int j = 0; j < 4; j++) {
            int idx = tid * 4 + j;
            int kk = idx >> 6, n = idx & 63;
            int gk = k0 + kk, gc = bx * 64 + n;
            Ws[kk][n] = (gk < K && gc < N) ? W[(long)gk * N + gc] : 0.0f;
        }
        __syncthreads();
#pragma unroll
        for (int kk = 0; kk < 16; kk++) {
            float a[4], w[4];
#pragma unroll
            for (int i = 0; i < 4; i++) a[i] = As[kk][ty * 4 + i];
#pragma unroll
            for (int j = 0; j < 4; j++) w[j] = Ws[kk][tx * 4 + j];
#pragma unroll
            for (int i = 0; i < 4; i++)
#pragma unroll
                for (int j = 0; j < 4; j++) acc[i][j] += a[i] * w[j];
        }
        __syncthreads();
    }
#pragma unroll
    for (int i = 0; i < 4; i++) {
        int r = row0 + i;
        if (r >= M) break;
#pragma unroll
        for (int j = 0; j < 4; j++) {
            int cN = col0 + j;
            if (cN < N) {
                float v = acc[i][j] + bias[cN];
                if (ACT == 1) v = fmaxf(v, 0.0f);
                if (ACT == 2) v = (v > 0.0f) ? v : (expf(v) - 1.0f);
                C[(long)r * ldc + cN] = v;
            }
        }
    }
}

// ---------------- ef rows: [hf | ht | |hf-ht| | hf*ht | t_norm | is_root] ------------
__global__ __launch_bounds__(256) void ef_kernel(const float* __restrict__ emb,
                                                 const int* __restrict__ bc,
                                                 const float* __restrict__ tv,
                                                 const float* __restrict__ isr,
                                                 float* __restrict__ ef) {
    int u = blockIdx.x;   // 0..8190
    int t = threadIdx.x;  // 256 threads * float2 = 512 cols/section
    const float* hf = emb + (long)FOCALR * HID;
    const float* ht = emb + (long)bc[u] * HID;
    float2 f = *(const float2*)(hf + 2 * t);
    float2 h = *(const float2*)(ht + 2 * t);
    float* row = ef + (long)u * EDIM;  // row base is 8B-aligned (2050*4 = 8200)
    *(float2*)(row + 2 * t) = f;
    *(float2*)(row + 512 + 2 * t) = h;
    float2 d; d.x = fabsf(f.x - h.x); d.y = fabsf(f.y - h.y);
    *(float2*)(row + 1024 + 2 * t) = d;
    float2 p; p.x = f.x * h.x; p.y = f.y * h.y;
    *(float2*)(row + 1536 + 2 * t) = p;
    if (t == 0) {
        row[2048] = tv[u] / (1.0f + 1e-8f);  // fp32: 1+1e-8 == 1
        row[2049] = isr[u];
    }
}

// ---------------- logits: z2 (8191x512) @ W_h3 (512x1) + b ---------------------------
__global__ __launch_bounds__(256) void logits_kernel(const float* __restrict__ z2,
                                                     const float* __restrict__ W3,
                                                     const float* __restrict__ b3,
                                                     float* __restrict__ out) {
    int wv = threadIdx.x >> 6, lane = threadIdx.x & 63;
    int row = blockIdx.x * 4 + wv;
    if (row >= NNODES) return;
    const float* zr = z2 + (long)row * HID;
    float s = 0.0f;
#pragma unroll
    for (int j = 0; j < 8; j++) s += zr[lane * 8 + j] * W3[lane * 8 + j];
    for (int o = 32; o; o >>= 1) s += __shfl_down(s, o);
    if (lane == 0) out[row] = s + b3[0];
}

// ---------------- softmax over 8191 logits (single block) ----------------------------
__global__ __launch_bounds__(1024) void softmax_kernel(const float* __restrict__ lg,
                                                       float* __restrict__ probs) {
    __shared__ float red[16];
    __shared__ float gmax_s, gsum_s;
    int t = threadIdx.x, wid = t >> 6, lane = t & 63;
    float m = -3.4e38f;
    for (int i = t; i < NNODES; i += 1024) m = fmaxf(m, lg[i]);
    for (int o = 32; o; o >>= 1) m = fmaxf(m, __shfl_down(m, o));
    if (lane == 0) red[wid] = m;
    __syncthreads();
    if (t == 0) {
        float g = red[0];
        for (int i = 1; i < 16; i++) g = fmaxf(g, red[i]);
        gmax_s = g;
    }
    __syncthreads();
    float gmax = gmax_s;
    float s = 0.0f;
    for (int i = t; i < NNODES; i += 1024) s += expf(lg[i] - gmax);
    for (int o = 32; o; o >>= 1) s += __shfl_down(s, o);
    if (lane == 0) red[wid] = s;
    __syncthreads();
    if (t == 0) {
        float g = 0.0f;
        for (int i = 0; i < 16; i++) g += red[i];
        gsum_s = g;
    }
    __syncthreads();
    float inv = 1.0f / gsum_s;
    for (int i = t; i < NNODES; i += 1024) probs[i] = expf(lg[i] - gmax) * inv;
}

extern "C" void kernel_launch(void* const* d_in, const int* in_sizes, int n_in,
                              void* d_out, int out_size, void* d_ws, size_t ws_size,
                              hipStream_t stream) {
    const int*   ns    = (const int*)d_in[0];
    const int*   ch0   = (const int*)d_in[1];
    const int*   ch1   = (const int*)d_in[2];
    const int*   par   = (const int*)d_in[3];
    const int*   neigh = (const int*)d_in[4];
    const int*   bc    = (const int*)d_in[5];
    const int*   cfl   = (const int*)d_in[6];
    const float* tv    = (const float*)d_in[7];
    const float* isr   = (const float*)d_in[8];
    const float* W1    = (const float*)d_in[9];
    const float* b1    = (const float*)d_in[10];
    const float* W2    = (const float*)d_in[11];
    const float* b2    = (const float*)d_in[12];
    const float* Wh1   = (const float*)d_in[13];
    const float* bh1   = (const float*)d_in[14];
    const float* Wh2   = (const float*)d_in[15];
    const float* bh2   = (const float*)d_in[16];
    const float* Wh3   = (const float*)d_in[17];
    const float* bh3   = (const float*)d_in[18];

    float* out = (float*)d_out;
    float* out_logits = out + OUT_LOGITS;
    float* out_probs  = out + OUT_PROBS;
    float* out_ef     = out + OUT_EF;
    float* out_emb    = out + OUT_EMB;
    float* out_focal  = out + OUT_FOCAL;

    char* ws = (char*)d_ws;
    float* c     = (float*)(ws);                       // 8191 floats (poison 0xAA < 0 == "not ready")
    float* flag2 = (float*)(ws + 40960);               // 8192 floats (poison != 1.0f)
    const size_t BUF = (size_t)NROWS * HID * sizeof(float);  // 16 MiB
    float* buf0 = (float*)(ws + 81920);                // y_post, later a2
    float* buf1 = (float*)(ws + 81920 + BUF);          // y, later z1
    float* buf2 = (float*)(ws + 81920 + 2 * BUF);      // h, later z2

    // focal_feat output
    focal_kernel<<<dim3(16), dim3(256), 0, stream>>>(cfl, out_focal);
    // tree recursions in projected 512-d space (resident spin kernels, topo order)
    post_kernel<<<dim3(256), dim3(256), 0, stream>>>(ns, ch0, ch1, W1, c, buf0);
    pre_kernel<<<dim3(256), dim3(256), 0, stream>>>(ns, par, cfl, W1, c, buf0, buf1, flag2);
    // GCN layer 1: h = relu(agg(y) + b1)
    gcn_agg_kernel<1, 1><<<dim3(NROWS), dim3(128), 0, stream>>>(buf1, neigh, b1, buf2);
    // GCN layer 2 aggregation: a2 = agg(h)
    gcn_agg_kernel<0, 0><<<dim3(NROWS), dim3(128), 0, stream>>>(buf2, neigh, b1, buf0);
    // emb = a2 @ W2 + b2  -> output
    gemm_kernel<0><<<dim3(8, 128), dim3(256), 0, stream>>>(buf0, W2, b2, out_emb,
                                                           NROWS, HID, HID, HID, HID);
    // ef rows -> output
    ef_kernel<<<dim3(NNODES), dim3(256), 0, stream>>>(out_emb, bc, tv, isr, out_ef);
    // z1 = elu(ef @ Wh1 + bh1)
    gemm_kernel<2><<<dim3(8, 128), dim3(256), 0, stream>>>(out_ef, Wh1, bh1, buf1,
                                                           NNODES, HID, EDIM, EDIM, HID);
    // z2 = elu(z1 @ Wh2 + bh2)
    gemm_kernel<2><<<dim3(8, 128), dim3(256), 0, stream>>>(buf1, Wh2, bh2, buf2,
                                                           NNODES, HID, HID, HID, HID);
    // logits -> output
    logits_kernel<<<dim3(2048), dim3(256), 0, stream>>>(buf2, Wh3, bh3, out_logits);
    // probs -> output
    softmax_kernel<<<dim3(1), dim3(1024), 0, stream>>>(out_logits, out_probs);
}

// Round 2
// 745.369 us; speedup vs baseline: 2.9452x; 2.9452x over previous
//
#include <hip/hip_runtime.h>
#include <hip/hip_bf16.h>
#include <math.h>

// Problem constants (fixed by reference)
#define NNODES 8191      // tree nodes, ids 0..8190 (topological: children < parent)
#define ROOT   8190
#define NROWS  8192      // tree nodes + appended focal row
#define FOCALR 8191
#define NLEAF  4096
#define HID    512
#define EDIM   2050

// Output layout (fp32 elements, concat in return order)
#define OUT_LOGITS 0
#define OUT_PROBS  8191
#define OUT_EF     16382
#define OUT_EMB    16807932   // 16382 + 8191*2050
#define OUT_FOCAL  21002236   // + 8192*512

typedef float  f32x4 __attribute__((ext_vector_type(4)));
typedef float  f32x2 __attribute__((ext_vector_type(2)));
typedef short  short8 __attribute__((ext_vector_type(8)));
typedef float  floatx4 __attribute__((ext_vector_type(4)));
typedef unsigned short u16x4 __attribute__((ext_vector_type(4)));
typedef unsigned short u16x2 __attribute__((ext_vector_type(2)));

__device__ __forceinline__ f32x4 ldg4(const float* p) { return *(const f32x4*)p; }
__device__ __forceinline__ f32x2 ldg2(const float* p) { return *(const f32x2*)p; }
__device__ __forceinline__ void stg4(float* p, f32x4 v) { *(f32x4*)p = v; }

// ---- L2-bypass (coherence-point) ops for same-kernel cross-wave handoff ----
__device__ __forceinline__ f32x4 ld4_cv(const float* p) {
    f32x4 v;
    asm volatile("global_load_dwordx4 %0, %1, off sc0 sc1\n\ts_waitcnt vmcnt(0)"
                 : "=v"(v) : "v"(p) : "memory");
    return v;
}
__device__ __forceinline__ void st4_wt(float* p, f32x4 v) {
    asm volatile("global_store_dwordx4 %0, %1, off sc0 sc1" :: "v"(p), "v"(v) : "memory");
}
__device__ __forceinline__ float ld_flag(const float* p) {
    float v;
    asm volatile("global_load_dword %0, %1, off sc0 sc1\n\ts_waitcnt vmcnt(0)"
                 : "=v"(v) : "v"(p) : "memory");
    return v;
}
// publish flag: drain this wave's prior (bypass) stores, then bypass-store flag
__device__ __forceinline__ void st_flag_ordered(float* p, float v) {
    asm volatile("s_waitcnt vmcnt(0)\n\tglobal_store_dword %0, %1, off sc0 sc1"
                 :: "v"(p), "v"(v) : "memory");
}

__device__ __forceinline__ unsigned short f2bf(float x) {
    union { float f; unsigned u; } u; u.f = x;
    unsigned r = u.u + 0x7fffu + ((u.u >> 16) & 1u);   // RNE, finite inputs
    return (unsigned short)(r >> 16);
}

// ---------------- focal one-hot output ----------------
__global__ void focal_kernel(const int* __restrict__ cfl, float* __restrict__ outf) {
    int i = blockIdx.x * 256 + threadIdx.x;
    if (i < NLEAF) outf[i] = (i == cfl[0]) ? 1.0f : 0.0f;
}

// ---------------- postorder: c[u] and y_post rows (512-d projected belief prop) --------
// Readiness flag for internal node a: c[a] > 0 (poison 0xAA.. = -3e-13 -> not ready).
__global__ __launch_bounds__(256) void post_kernel(const int* __restrict__ ns,
                                                   const int* __restrict__ ch0,
                                                   const int* __restrict__ ch1,
                                                   const float* __restrict__ W1,
                                                   float* c, float* __restrict__ ypost) {
    int gtid = blockIdx.x * 256 + threadIdx.x;
    int wave = gtid >> 6, lane = gtid & 63;
    const int nw = 1024;
    for (int u = wave; u < NNODES; u += nw) {
        if (ns[u] >= 0) continue;  // leaf
        int a = ch0[u], b = ch1[u];
        int nsa = ns[a], nsb = ns[b];
        float ca = 0.0f, cb = 0.0f;
        if (nsa < 0) { do { ca = ld_flag(&c[a]); } while (ca <= 0.0f); }
        if (nsb < 0) { do { cb = ld_flag(&c[b]); } while (cb <= 0.0f); }
        float cu = 1.0f / (3.0f - ca - cb);
        const float* ra = (nsa >= 0) ? (W1 + (long)nsa * HID) : (ypost + (long)a * HID);
        const float* rb = (nsb >= 0) ? (W1 + (long)nsb * HID) : (ypost + (long)b * HID);
        float* dst = ypost + (long)u * HID;
        for (int j = lane * 4; j < HID; j += 256) {
            f32x4 x = (nsa >= 0) ? ldg4(ra + j) : ld4_cv(ra + j);
            f32x4 y = (nsb >= 0) ? ldg4(rb + j) : ld4_cv(rb + j);
            st4_wt(dst + j, (x + y) * cu);
        }
        if (lane == 0) st_flag_ordered(&c[u], cu);
    }
}

// ---------------- preorder: y[u] = y_post[u] + c[u]*y[parent]; leaves/focal = W1 rows --
__global__ __launch_bounds__(256) void pre_kernel(const int* __restrict__ ns,
                                                  const int* __restrict__ par,
                                                  const int* __restrict__ cflp,
                                                  const float* __restrict__ W1,
                                                  const float* __restrict__ c,
                                                  const float* __restrict__ ypost,
                                                  float* __restrict__ y, float* flag2) {
    int gtid = blockIdx.x * 256 + threadIdx.x;
    int wave = gtid >> 6, lane = gtid & 63;
    const int nw = 1024;
    for (int u = (NROWS - 1) - wave; u >= 0; u -= nw) {
        float* dst = y + (long)u * HID;
        if (u == FOCALR) {  // focal row = W1[cfl,:]; nothing in-kernel reads it
            const float* src = W1 + (long)cflp[0] * HID;
            for (int j = lane * 4; j < HID; j += 256) stg4(dst + j, ldg4(src + j));
            continue;
        }
        if (ns[u] >= 0) {   // leaf: y = W1[ns[u],:]; nothing in-kernel reads it
            const float* src = W1 + (long)ns[u] * HID;
            for (int j = lane * 4; j < HID; j += 256) stg4(dst + j, ldg4(src + j));
            continue;
        }
        if (u == ROOT) {
            const float* src = ypost + (long)u * HID;
            for (int j = lane * 4; j < HID; j += 256) st4_wt(dst + j, ldg4(src + j));
        } else {
            int p = par[u];
            while (ld_flag(&flag2[p]) != 1.0f) { }
            float cu = c[u];  // written by previous dispatch -> cached read OK
            const float* sp = ypost + (long)u * HID;
            const float* pp = y + (long)p * HID;
            for (int j = lane * 4; j < HID; j += 256) {
                f32x4 a = ldg4(sp + j);
                f32x4 b = ld4_cv(pp + j);
                st4_wt(dst + j, a + cu * b);
            }
        }
        if (lane == 0) st_flag_ordered(&flag2[u], 1.0f);
    }
}

// ---------------- GCN neighbor aggregation in 512-d -----------------------------------
template <int RELU, int BIAS>
__global__ __launch_bounds__(128) void gcn_agg_kernel(const float* __restrict__ xin,
                                                      const int* __restrict__ neigh,
                                                      const float* __restrict__ bias,
                                                      float* __restrict__ xout) {
    int u = blockIdx.x;
    int t = threadIdx.x;
    int n0 = neigh[u * 3 + 0], n1 = neigh[u * 3 + 1], n2 = neigh[u * 3 + 2];
    float deg = 1.0f + (n0 >= 0) + (n1 >= 0) + (n2 >= 0);
    f32x4 s = ldg4(xin + (long)u * HID + t * 4);
    if (n0 >= 0) s += ldg4(xin + (long)n0 * HID + t * 4);
    if (n1 >= 0) s += ldg4(xin + (long)n1 * HID + t * 4);
    if (n2 >= 0) s += ldg4(xin + (long)n2 * HID + t * 4);
    s *= (1.0f / deg);
    if (BIAS) s += ldg4(bias + t * 4);
    if (RELU) { s.x = fmaxf(s.x, 0.f); s.y = fmaxf(s.y, 0.f); s.z = fmaxf(s.z, 0.f); s.w = fmaxf(s.w, 0.f); }
    stg4(xout + (long)u * HID + t * 4, s);
}

// ---------------- bf16 MFMA GEMM: C = act(A@W + bias) ---------------------------------
// A: MxK fp32 (lda), W: KxN fp32 row-major (N=512 exact multiple of 128), C fp32 (ldc).
// Block 256 thr = 2x2 waves, tile 128x128, BK=32 (one 16x16x32 MFMA per chunk).
// ACT: 0 none, 2 elu.  AVEC: A global load width (4 or 2 floats) for alignment.
template <int ACT, int AVEC>
__global__ __launch_bounds__(256, 2) void gemm_bf16(const float* __restrict__ A,
                                                    const float* __restrict__ W,
                                                    const float* __restrict__ bias,
                                                    float* __restrict__ C,
                                                    int M, int N_, int K, int lda, int ldc) {
    __shared__ unsigned short As[128 * 40];  // [m][k], k padded 32->40 (80B rows, 16B-aligned frags)
    __shared__ unsigned short Ws[128 * 40];  // [n][k] (transposed on staging)
    const int tid = threadIdx.x;
    const int lane = tid & 63;
    const int wm = (tid >> 6) >> 1, wn = (tid >> 6) & 1;
    const int bm = blockIdx.y * 128, bn = blockIdx.x * 128;
    const int kq = lane >> 4, lr = lane & 15;
    floatx4 acc[4][4] = {};

    for (int k0 = 0; k0 < K; k0 += 32) {
        // ---- stage A tile 128x32 (fp32 -> bf16) ----
        if (AVEC == 4) {
#pragma unroll
            for (int i = 0; i < 4; i++) {
                int f = tid + i * 256;             // 1024 float4
                int row = f >> 3, c4 = f & 7;
                int gr = bm + row, gk = k0 + c4 * 4;
                f32x4 v = {0.f, 0.f, 0.f, 0.f};
                if (gr < M) {
                    if (gk + 3 < K) v = ldg4(A + (long)gr * lda + gk);
                    else {
#pragma unroll
                        for (int q = 0; q < 4; q++) if (gk + q < K) v[q] = A[(long)gr * lda + gk + q];
                    }
                }
                u16x4 h; h[0] = f2bf(v[0]); h[1] = f2bf(v[1]); h[2] = f2bf(v[2]); h[3] = f2bf(v[3]);
                *(u16x4*)&As[row * 40 + c4 * 4] = h;
            }
        } else {
#pragma unroll
            for (int i = 0; i < 8; i++) {
                int f = tid + i * 256;             // 2048 float2
                int row = f >> 4, c2 = f & 15;
                int gr = bm + row, gk = k0 + c2 * 2;
                f32x2 v = {0.f, 0.f};
                if (gr < M) {
                    if (gk + 1 < K) v = ldg2(A + (long)gr * lda + gk);
                    else {
#pragma unroll
                        for (int q = 0; q < 2; q++) if (gk + q < K) v[q] = A[(long)gr * lda + gk + q];
                    }
                }
                u16x2 h; h[0] = f2bf(v[0]); h[1] = f2bf(v[1]);
                *(u16x2*)&As[row * 40 + c2 * 2] = h;
            }
        }
        // ---- stage W tile 32x128, transposed to [n][k] ----
#pragma unroll
        for (int i = 0; i < 4; i++) {
            int f = tid + i * 256;                 // 1024 float4: 32 k-rows x 32 f4
            int kr = f >> 5, n4 = f & 31;
            int gk = k0 + kr;
            f32x4 v = {0.f, 0.f, 0.f, 0.f};
            if (gk < K) v = ldg4(W + (long)gk * N_ + bn + n4 * 4);
#pragma unroll
            for (int q = 0; q < 4; q++) Ws[(n4 * 4 + q) * 40 + kr] = f2bf(v[q]);
        }
        __syncthreads();
        // ---- fragments + MFMA ----
        short8 af[4], bfr[4];
#pragma unroll
        for (int t = 0; t < 4; t++) {
            af[t]  = *(short8*)&As[(wm * 64 + t * 16 + lr) * 40 + kq * 8];
            bfr[t] = *(short8*)&Ws[(wn * 64 + t * 16 + lr) * 40 + kq * 8];
        }
#pragma unroll
        for (int i = 0; i < 4; i++)
#pragma unroll
            for (int j = 0; j < 4; j++)
                acc[i][j] = __builtin_amdgcn_mfma_f32_16x16x32_bf16(af[i], bfr[j], acc[i][j], 0, 0, 0);
        __syncthreads();
    }
    // ---- epilogue: row=(lane>>4)*4+reg, col=lane&15 ----
#pragma unroll
    for (int i = 0; i < 4; i++) {
        int row0 = bm + wm * 64 + i * 16 + kq * 4;
#pragma unroll
        for (int j = 0; j < 4; j++) {
            int col = bn + wn * 64 + j * 16 + lr;
            float bv = bias[col];
#pragma unroll
            for (int r = 0; r < 4; r++) {
                int gr = row0 + r;
                if (gr < M) {
                    float v = acc[i][j][r] + bv;
                    if (ACT == 2) v = (v > 0.0f) ? v : (expf(v) - 1.0f);
                    C[(long)gr * ldc + col] = v;
                }
            }
        }
    }
}

// ---------------- ef rows: [hf | ht | |hf-ht| | hf*ht | t_norm | is_root] -------------
__global__ __launch_bounds__(256) void ef_kernel(const float* __restrict__ emb,
                                                 const int* __restrict__ bc,
                                                 const float* __restrict__ tv,
                                                 const float* __restrict__ isr,
                                                 float* __restrict__ ef) {
    int u = blockIdx.x;
    int t = threadIdx.x;
    const float* hf = emb + (long)FOCALR * HID;
    const float* ht = emb + (long)bc[u] * HID;
    f32x2 f = ldg2(hf + 2 * t);
    f32x2 h = ldg2(ht + 2 * t);
    float* row = ef + (long)u * EDIM;
    *(f32x2*)(row + 2 * t) = f;
    *(f32x2*)(row + 512 + 2 * t) = h;
    f32x2 d; d[0] = fabsf(f[0] - h[0]); d[1] = fabsf(f[1] - h[1]);
    *(f32x2*)(row + 1024 + 2 * t) = d;
    f32x2 p; p[0] = f[0] * h[0]; p[1] = f[1] * h[1];
    *(f32x2*)(row + 1536 + 2 * t) = p;
    if (t == 0) {
        row[2048] = tv[u];   // (T_MAX-T_MIN+1e-8) rounds to 1.0f in fp32
        row[2049] = isr[u];
    }
}

// ---------------- logits: z2 (8191x512) @ W_h3 (512x1) + b ----------------------------
__global__ __launch_bounds__(256) void logits_kernel(const float* __restrict__ z2,
                                                     const float* __restrict__ W3,
                                                     const float* __restrict__ b3,
                                                     float* __restrict__ out) {
    int wv = threadIdx.x >> 6, lane = threadIdx.x & 63;
    int row = blockIdx.x * 4 + wv;
    if (row >= NNODES) return;
    const float* zr = z2 + (long)row * HID;
    float s = 0.0f;
#pragma unroll
    for (int j = 0; j < 8; j++) s += zr[lane * 8 + j] * W3[lane * 8 + j];
    for (int o = 32; o; o >>= 1) s += __shfl_down(s, o);
    if (lane == 0) out[row] = s + b3[0];
}

// ---------------- softmax over 8191 logits (single block) -----------------------------
__global__ __launch_bounds__(1024) void softmax_kernel(const float* __restrict__ lg,
                                                       float* __restrict__ probs) {
    __shared__ float red[16];
    __shared__ float gmax_s, gsum_s;
    int t = threadIdx.x, wid = t >> 6, lane = t & 63;
    float m = -3.4e38f;
    for (int i = t; i < NNODES; i += 1024) m = fmaxf(m, lg[i]);
    for (int o = 32; o; o >>= 1) m = fmaxf(m, __shfl_down(m, o));
    if (lane == 0) red[wid] = m;
    __syncthreads();
    if (t == 0) {
        float g = red[0];
        for (int i = 1; i < 16; i++) g = fmaxf(g, red[i]);
        gmax_s = g;
    }
    __syncthreads();
    float gmax = gmax_s;
    float s = 0.0f;
    for (int i = t; i < NNODES; i += 1024) s += expf(lg[i] - gmax);
    for (int o = 32; o; o >>= 1) s += __shfl_down(s, o);
    if (lane == 0) red[wid] = s;
    __syncthreads();
    if (t == 0) {
        float g = 0.0f;
        for (int i = 0; i < 16; i++) g += red[i];
        gsum_s = g;
    }
    __syncthreads();
    float inv = 1.0f / gsum_s;
    for (int i = t; i < NNODES; i += 1024) probs[i] = expf(lg[i] - gmax) * inv;
}

extern "C" void kernel_launch(void* const* d_in, const int* in_sizes, int n_in,
                              void* d_out, int out_size, void* d_ws, size_t ws_size,
                              hipStream_t stream) {
    const int*   ns    = (const int*)d_in[0];
    const int*   ch0   = (const int*)d_in[1];
    const int*   ch1   = (const int*)d_in[2];
    const int*   par   = (const int*)d_in[3];
    const int*   neigh = (const int*)d_in[4];
    const int*   bc    = (const int*)d_in[5];
    const int*   cfl   = (const int*)d_in[6];
    const float* tv    = (const float*)d_in[7];
    const float* isr   = (const float*)d_in[8];
    const float* W1    = (const float*)d_in[9];
    const float* b1    = (const float*)d_in[10];
    const float* W2    = (const float*)d_in[11];
    const float* b2    = (const float*)d_in[12];
    const float* Wh1   = (const float*)d_in[13];
    const float* bh1   = (const float*)d_in[14];
    const float* Wh2   = (const float*)d_in[15];
    const float* bh2   = (const float*)d_in[16];
    const float* Wh3   = (const float*)d_in[17];
    const float* bh3   = (const float*)d_in[18];

    float* out = (float*)d_out;
    float* out_logits = out + OUT_LOGITS;
    float* out_probs  = out + OUT_PROBS;
    float* out_ef     = out + OUT_EF;
    float* out_emb    = out + OUT_EMB;
    float* out_focal  = out + OUT_FOCAL;

    char* ws = (char*)d_ws;
    float* c     = (float*)(ws);                       // 8191 floats
    float* flag2 = (float*)(ws + 40960);               // 8192 floats
    const size_t BUF = (size_t)NROWS * HID * sizeof(float);  // 16 MiB
    float* buf0 = (float*)(ws + 81920);                // y_post, later a2
    float* buf1 = (float*)(ws + 81920 + BUF);          // y, later z1
    float* buf2 = (float*)(ws + 81920 + 2 * BUF);      // h, later z2

    focal_kernel<<<dim3(16), dim3(256), 0, stream>>>(cfl, out_focal);
    post_kernel<<<dim3(256), dim3(256), 0, stream>>>(ns, ch0, ch1, W1, c, buf0);
    pre_kernel<<<dim3(256), dim3(256), 0, stream>>>(ns, par, cfl, W1, c, buf0, buf1, flag2);
    // GCN layer 1: h = relu(agg(y) + b1)
    gcn_agg_kernel<1, 1><<<dim3(NROWS), dim3(128), 0, stream>>>(buf1, neigh, b1, buf2);
    // GCN layer 2 aggregation: a2 = agg(h)
    gcn_agg_kernel<0, 0><<<dim3(NROWS), dim3(128), 0, stream>>>(buf2, neigh, b1, buf0);
    // emb = a2 @ W2 + b2  (M=8192, K=512)
    gemm_bf16<0, 4><<<dim3(4, 64), dim3(256), 0, stream>>>(buf0, W2, b2, out_emb,
                                                           NROWS, HID, HID, HID, HID);
    // ef rows
    ef_kernel<<<dim3(NNODES), dim3(256), 0, stream>>>(out_emb, bc, tv, isr, out_ef);
    // z1 = elu(ef @ Wh1 + bh1)  (M=8191, K=2050; ef rows only 8B-aligned -> AVEC=2)
    gemm_bf16<2, 2><<<dim3(4, 64), dim3(256), 0, stream>>>(out_ef, Wh1, bh1, buf1,
                                                           NNODES, HID, EDIM, EDIM, HID);
    // z2 = elu(z1 @ Wh2 + bh2)
    gemm_bf16<2, 4><<<dim3(4, 64), dim3(256), 0, stream>>>(buf1, Wh2, bh2, buf2,
                                                           NNODES, HID, HID, HID, HID);
    logits_kernel<<<dim3(2048), dim3(256), 0, stream>>>(buf2, Wh3, bh3, out_logits);
    softmax_kernel<<<dim3(1), dim3(1024), 0, stream>>>(out_logits, out_probs);
}

// Round 3
// 450.516 us; speedup vs baseline: 4.8727x; 1.6545x over previous
//
#include <hip/hip_runtime.h>
#include <hip/hip_bf16.h>
#include <math.h>

// Problem constants (fixed by reference)
#define NNODES 8191      // tree nodes, ids 0..8190 (topological: children < parent)
#define ROOT   8190
#define NROWS  8192      // tree nodes + appended focal row
#define FOCALR 8191
#define NLEAF  4096
#define HID    512
#define EDIM   2050

// Output layout (fp32 elements, concat in return order)
#define OUT_LOGITS 0
#define OUT_PROBS  8191
#define OUT_EF     16382
#define OUT_EMB    16807932   // 16382 + 8191*2050
#define OUT_FOCAL  21002236   // + 8192*512

typedef float  f32x4 __attribute__((ext_vector_type(4)));
typedef float  f32x2 __attribute__((ext_vector_type(2)));
typedef float  floatx4 __attribute__((ext_vector_type(4)));
typedef short  short8 __attribute__((ext_vector_type(8)));
typedef unsigned short u16;
typedef unsigned short u16x8 __attribute__((ext_vector_type(8)));
typedef unsigned short u16x4 __attribute__((ext_vector_type(4)));

__device__ __forceinline__ f32x4 ldg4(const float* p) { return *(const f32x4*)p; }
__device__ __forceinline__ f32x2 ldg2(const float* p) { return *(const f32x2*)p; }
__device__ __forceinline__ void stg4(float* p, f32x4 v) { *(f32x4*)p = v; }

// ---- L2-bypass (coherence-point) ops for same-kernel cross-wave handoff ----
__device__ __forceinline__ f32x4 ld4_cv(const float* p) {
    f32x4 v;
    asm volatile("global_load_dwordx4 %0, %1, off sc0 sc1\n\ts_waitcnt vmcnt(0)"
                 : "=v"(v) : "v"(p) : "memory");
    return v;
}
__device__ __forceinline__ void st4_wt(float* p, f32x4 v) {
    asm volatile("global_store_dwordx4 %0, %1, off sc0 sc1" :: "v"(p), "v"(v) : "memory");
}
__device__ __forceinline__ float ld_flag(const float* p) {
    float v;
    asm volatile("global_load_dword %0, %1, off sc0 sc1\n\ts_waitcnt vmcnt(0)"
                 : "=v"(v) : "v"(p) : "memory");
    return v;
}
__device__ __forceinline__ void st_flag_ordered(float* p, float v) {
    asm volatile("s_waitcnt vmcnt(0)\n\tglobal_store_dword %0, %1, off sc0 sc1"
                 :: "v"(p), "v"(v) : "memory");
}

__device__ __forceinline__ u16 f2bf(float x) {
    union { float f; unsigned u; } u; u.f = x;
    unsigned r = u.u + 0x7fffu + ((u.u >> 16) & 1u);   // RNE, finite inputs
    return (u16)(r >> 16);
}
__device__ __forceinline__ float b2f(u16 h) {
    union { unsigned u; float f; } x; x.u = ((unsigned)h) << 16; return x.f;
}

// ---------------- focal one-hot output ----------------
__global__ void focal_kernel(const int* __restrict__ cfl, float* __restrict__ outf) {
    int i = blockIdx.x * 256 + threadIdx.x;
    if (i < NLEAF) outf[i] = (i == cfl[0]) ? 1.0f : 0.0f;
}

// ---------------- weight pre-transpose: W (K x N fp32, N=512) -> WT (N x K bf16) ------
__global__ __launch_bounds__(256) void transpose_bf16(const float* __restrict__ W,
                                                      u16* __restrict__ WT, int K) {
    __shared__ float tile[32][33];
    int tx = threadIdx.x & 31, ty = threadIdx.x >> 5;   // 32 x 8
    int n0 = blockIdx.x * 32, k0 = blockIdx.y * 32;
#pragma unroll
    for (int i = 0; i < 4; i++)
        tile[ty + i * 8][tx] = W[(long)(k0 + ty + i * 8) * HID + n0 + tx];
    __syncthreads();
#pragma unroll
    for (int i = 0; i < 4; i++)
        WT[(long)(n0 + ty + i * 8) * K + k0 + tx] = f2bf(tile[tx][ty + i * 8]);
}

// ---------------- postorder: c[u] and y_post rows (512-d projected belief prop) -------
__global__ __launch_bounds__(256) void post_kernel(const int* __restrict__ ns,
                                                   const int* __restrict__ ch0,
                                                   const int* __restrict__ ch1,
                                                   const float* __restrict__ W1,
                                                   float* c, float* __restrict__ ypost) {
    int gtid = blockIdx.x * 256 + threadIdx.x;
    int wave = gtid >> 6, lane = gtid & 63;
    const int nw = 1024;
    for (int u = wave; u < NNODES; u += nw) {
        if (ns[u] >= 0) continue;  // leaf
        int a = ch0[u], b = ch1[u];
        int nsa = ns[a], nsb = ns[b];
        float ca = 0.0f, cb = 0.0f;
        if (nsa < 0) { do { ca = ld_flag(&c[a]); } while (ca <= 0.0f); }
        if (nsb < 0) { do { cb = ld_flag(&c[b]); } while (cb <= 0.0f); }
        float cu = 1.0f / (3.0f - ca - cb);
        const float* ra = (nsa >= 0) ? (W1 + (long)nsa * HID) : (ypost + (long)a * HID);
        const float* rb = (nsb >= 0) ? (W1 + (long)nsb * HID) : (ypost + (long)b * HID);
        float* dst = ypost + (long)u * HID;
        for (int j = lane * 4; j < HID; j += 256) {
            f32x4 x = (nsa >= 0) ? ldg4(ra + j) : ld4_cv(ra + j);
            f32x4 y = (nsb >= 0) ? ldg4(rb + j) : ld4_cv(rb + j);
            st4_wt(dst + j, (x + y) * cu);
        }
        if (lane == 0) st_flag_ordered(&c[u], cu);
    }
}

// ---------------- preorder: y[u] = y_post[u] + c[u]*y[parent]; leaves/focal = W1 rows --
__global__ __launch_bounds__(256) void pre_kernel(const int* __restrict__ ns,
                                                  const int* __restrict__ par,
                                                  const int* __restrict__ cflp,
                                                  const float* __restrict__ W1,
                                                  const float* __restrict__ c,
                                                  const float* __restrict__ ypost,
                                                  float* __restrict__ y, float* flag2) {
    int gtid = blockIdx.x * 256 + threadIdx.x;
    int wave = gtid >> 6, lane = gtid & 63;
    const int nw = 1024;
    for (int u = (NROWS - 1) - wave; u >= 0; u -= nw) {
        float* dst = y + (long)u * HID;
        if (u == FOCALR) {
            const float* src = W1 + (long)cflp[0] * HID;
            for (int j = lane * 4; j < HID; j += 256) stg4(dst + j, ldg4(src + j));
            continue;
        }
        if (ns[u] >= 0) {
            const float* src = W1 + (long)ns[u] * HID;
            for (int j = lane * 4; j < HID; j += 256) stg4(dst + j, ldg4(src + j));
            continue;
        }
        if (u == ROOT) {
            const float* src = ypost + (long)u * HID;
            for (int j = lane * 4; j < HID; j += 256) st4_wt(dst + j, ldg4(src + j));
        } else {
            int p = par[u];
            while (ld_flag(&flag2[p]) != 1.0f) { }
            float cu = c[u];
            const float* sp = ypost + (long)u * HID;
            const float* pp = y + (long)p * HID;
            for (int j = lane * 4; j < HID; j += 256) {
                f32x4 a = ldg4(sp + j);
                f32x4 b = ld4_cv(pp + j);
                st4_wt(dst + j, a + cu * b);
            }
        }
        if (lane == 0) st_flag_ordered(&flag2[u], 1.0f);
    }
}

// ---------------- GCN neighbor aggregation in 512-d -----------------------------------
// OBF=1: write bf16 instead of fp32
template <int RELU, int BIAS, int OBF>
__global__ __launch_bounds__(128) void gcn_agg_kernel(const float* __restrict__ xin,
                                                      const int* __restrict__ neigh,
                                                      const float* __restrict__ bias,
                                                      float* __restrict__ xoutf,
                                                      u16* __restrict__ xoutb) {
    int u = blockIdx.x;
    int t = threadIdx.x;
    int n0 = neigh[u * 3 + 0], n1 = neigh[u * 3 + 1], n2 = neigh[u * 3 + 2];
    float deg = 1.0f + (n0 >= 0) + (n1 >= 0) + (n2 >= 0);
    f32x4 s = ldg4(xin + (long)u * HID + t * 4);
    if (n0 >= 0) s += ldg4(xin + (long)n0 * HID + t * 4);
    if (n1 >= 0) s += ldg4(xin + (long)n1 * HID + t * 4);
    if (n2 >= 0) s += ldg4(xin + (long)n2 * HID + t * 4);
    s *= (1.0f / deg);
    if (BIAS) s += ldg4(bias + t * 4);
    if (RELU) { s.x = fmaxf(s.x, 0.f); s.y = fmaxf(s.y, 0.f); s.z = fmaxf(s.z, 0.f); s.w = fmaxf(s.w, 0.f); }
    if (OBF) {
        u16x4 h; h[0] = f2bf(s.x); h[1] = f2bf(s.y); h[2] = f2bf(s.z); h[3] = f2bf(s.w);
        *(u16x4*)(xoutb + (long)u * HID + t * 4) = h;
    } else {
        stg4(xoutf + (long)u * HID + t * 4, s);
    }
}

// ---------------- bf16 MFMA GEMM v3 ---------------------------------------------------
// A: bf16 MxK row-major (stride K; FUSE_EF: A = emb_bf 8192x512, K=2048 virtual).
// WT: bf16 NxK (N=512). Tile 128x128, BK=64, 4 waves (2x2), padded LDS rows (72 shorts).
// ACT: 0 none, 2 elu. Cf/Cbf nullable fp32/bf16 outputs (ldc = HID).
// FUSE_EF epilogue adds tv[row]*Wtail[col] + isr[row]*Wtail[512+col] (Wh1 rows 2048/2049).
template <int ACT, int FUSE_EF>
__global__ __launch_bounds__(256) void gemm_v3(const u16* __restrict__ Abf,
                                               const u16* __restrict__ WT,
                                               const float* __restrict__ bias,
                                               const int* __restrict__ bc,
                                               const float* __restrict__ tv,
                                               const float* __restrict__ isr,
                                               const float* __restrict__ Wtail,
                                               float* __restrict__ Cf,
                                               u16* __restrict__ Cbf,
                                               int M, int K) {
    __shared__ u16 As[128 * 72];
    __shared__ u16 Ws[128 * 72];
    const int tid = threadIdx.x, lane = tid & 63;
    const int wm = (tid >> 6) >> 1, wn = (tid >> 6) & 1;
    const int bm = blockIdx.y * 128, bn = blockIdx.x * 128;
    const int kq = lane >> 4, lr = lane & 15;
    const int srow = tid >> 3, schunk = tid & 7;
    floatx4 acc[4][4] = {};

    for (int k0 = 0; k0 < K; k0 += 64) {
        // ---- stage A 128x64 bf16 ----
#pragma unroll
        for (int i = 0; i < 4; i++) {
            int row = srow + i * 32;
            int gr = bm + row;
            u16x8 v = {0, 0, 0, 0, 0, 0, 0, 0};
            if (!FUSE_EF) {
                if (gr < M) v = *(const u16x8*)(Abf + (long)gr * K + k0 + schunk * 8);
            } else {
                if (gr < M) {
                    int c = (k0 & 511) + schunk * 8;
                    int sec = k0 >> 9;   // BK=64 never straddles 512-col sections
                    u16x8 hf8 = *(const u16x8*)(Abf + (long)FOCALR * HID + c);
                    if (sec == 0) v = hf8;
                    else {
                        u16x8 ht8 = *(const u16x8*)(Abf + (long)bc[gr] * HID + c);
                        if (sec == 1) v = ht8;
                        else if (sec == 2) {
#pragma unroll
                            for (int q = 0; q < 8; q++) v[q] = f2bf(fabsf(b2f(hf8[q]) - b2f(ht8[q])));
                        } else {
#pragma unroll
                            for (int q = 0; q < 8; q++) v[q] = f2bf(b2f(hf8[q]) * b2f(ht8[q]));
                        }
                    }
                }
            }
            *(u16x8*)&As[row * 72 + schunk * 8] = v;
        }
        // ---- stage B 128x64 bf16 from pre-transposed WT (pure copy) ----
#pragma unroll
        for (int i = 0; i < 4; i++) {
            int row = srow + i * 32;
            u16x8 v = *(const u16x8*)(WT + (long)(bn + row) * K + k0 + schunk * 8);
            *(u16x8*)&Ws[row * 72 + schunk * 8] = v;
        }
        __syncthreads();
        // ---- 32 MFMAs per wave ----
#pragma unroll
        for (int kc = 0; kc < 2; kc++) {
            short8 af[4], bf8[4];
#pragma unroll
            for (int t2 = 0; t2 < 4; t2++) {
                af[t2]  = *(short8*)&As[(wm * 64 + t2 * 16 + lr) * 72 + kc * 32 + kq * 8];
                bf8[t2] = *(short8*)&Ws[(wn * 64 + t2 * 16 + lr) * 72 + kc * 32 + kq * 8];
            }
#pragma unroll
            for (int i2 = 0; i2 < 4; i2++)
#pragma unroll
                for (int j = 0; j < 4; j++)
                    acc[i2][j] = __builtin_amdgcn_mfma_f32_16x16x32_bf16(af[i2], bf8[j], acc[i2][j], 0, 0, 0);
        }
        __syncthreads();
    }
    // ---- epilogue: row=(lane>>4)*4+reg, col=lane&15 ----
#pragma unroll
    for (int i = 0; i < 4; i++) {
        int row0 = bm + wm * 64 + i * 16 + kq * 4;
#pragma unroll
        for (int j = 0; j < 4; j++) {
            int col = bn + wn * 64 + j * 16 + lr;
            float bv = bias[col];
            float t0 = 0.f, t1 = 0.f;
            if (FUSE_EF) { t0 = Wtail[col]; t1 = Wtail[512 + col]; }
#pragma unroll
            for (int r = 0; r < 4; r++) {
                int gr = row0 + r;
                if (gr < M) {
                    float v = acc[i][j][r] + bv;
                    if (FUSE_EF) v += tv[gr] * t0 + isr[gr] * t1;
                    if (ACT == 2) v = (v > 0.0f) ? v : (expf(v) - 1.0f);
                    if (Cf)  Cf[(long)gr * HID + col] = v;
                    if (Cbf) Cbf[(long)gr * HID + col] = f2bf(v);
                }
            }
        }
    }
}

// ---------------- ef rows: [hf | ht | |hf-ht| | hf*ht | t_norm | is_root] -------------
__global__ __launch_bounds__(256) void ef_kernel(const float* __restrict__ emb,
                                                 const int* __restrict__ bc,
                                                 const float* __restrict__ tv,
                                                 const float* __restrict__ isr,
                                                 float* __restrict__ ef) {
    int u = blockIdx.x;
    int t = threadIdx.x;
    const float* hf = emb + (long)FOCALR * HID;
    const float* ht = emb + (long)bc[u] * HID;
    f32x2 f = ldg2(hf + 2 * t);
    f32x2 h = ldg2(ht + 2 * t);
    float* row = ef + (long)u * EDIM;
    *(f32x2*)(row + 2 * t) = f;
    *(f32x2*)(row + 512 + 2 * t) = h;
    f32x2 d; d[0] = fabsf(f[0] - h[0]); d[1] = fabsf(f[1] - h[1]);
    *(f32x2*)(row + 1024 + 2 * t) = d;
    f32x2 p; p[0] = f[0] * h[0]; p[1] = f[1] * h[1];
    *(f32x2*)(row + 1536 + 2 * t) = p;
    if (t == 0) {
        row[2048] = tv[u];
        row[2049] = isr[u];
    }
}

// ---------------- logits: z2 (8191x512) @ W_h3 (512x1) + b ----------------------------
__global__ __launch_bounds__(256) void logits_kernel(const float* __restrict__ z2,
                                                     const float* __restrict__ W3,
                                                     const float* __restrict__ b3,
                                                     float* __restrict__ out) {
    int wv = threadIdx.x >> 6, lane = threadIdx.x & 63;
    int row = blockIdx.x * 4 + wv;
    if (row >= NNODES) return;
    const float* zr = z2 + (long)row * HID;
    float s = 0.0f;
#pragma unroll
    for (int j = 0; j < 8; j++) s += zr[lane * 8 + j] * W3[lane * 8 + j];
    for (int o = 32; o; o >>= 1) s += __shfl_down(s, o);
    if (lane == 0) out[row] = s + b3[0];
}

// ---------------- softmax over 8191 logits (single block) -----------------------------
__global__ __launch_bounds__(1024) void softmax_kernel(const float* __restrict__ lg,
                                                       float* __restrict__ probs) {
    __shared__ float red[16];
    __shared__ float gmax_s, gsum_s;
    int t = threadIdx.x, wid = t >> 6, lane = t & 63;
    float m = -3.4e38f;
    for (int i = t; i < NNODES; i += 1024) m = fmaxf(m, lg[i]);
    for (int o = 32; o; o >>= 1) m = fmaxf(m, __shfl_down(m, o));
    if (lane == 0) red[wid] = m;
    __syncthreads();
    if (t == 0) {
        float g = red[0];
        for (int i = 1; i < 16; i++) g = fmaxf(g, red[i]);
        gmax_s = g;
    }
    __syncthreads();
    float gmax = gmax_s;
    float s = 0.0f;
    for (int i = t; i < NNODES; i += 1024) s += expf(lg[i] - gmax);
    for (int o = 32; o; o >>= 1) s += __shfl_down(s, o);
    if (lane == 0) red[wid] = s;
    __syncthreads();
    if (t == 0) {
        float g = 0.0f;
        for (int i = 0; i < 16; i++) g += red[i];
        gsum_s = g;
    }
    __syncthreads();
    float inv = 1.0f / gsum_s;
    for (int i = t; i < NNODES; i += 1024) probs[i] = expf(lg[i] - gmax) * inv;
}

extern "C" void kernel_launch(void* const* d_in, const int* in_sizes, int n_in,
                              void* d_out, int out_size, void* d_ws, size_t ws_size,
                              hipStream_t stream) {
    const int*   ns    = (const int*)d_in[0];
    const int*   ch0   = (const int*)d_in[1];
    const int*   ch1   = (const int*)d_in[2];
    const int*   par   = (const int*)d_in[3];
    const int*   neigh = (const int*)d_in[4];
    const int*   bc    = (const int*)d_in[5];
    const int*   cfl   = (const int*)d_in[6];
    const float* tv    = (const float*)d_in[7];
    const float* isr   = (const float*)d_in[8];
    const float* W1    = (const float*)d_in[9];
    const float* b1    = (const float*)d_in[10];
    const float* W2    = (const float*)d_in[11];
    const float* b2    = (const float*)d_in[12];
    const float* Wh1   = (const float*)d_in[13];
    const float* bh1   = (const float*)d_in[14];
    const float* Wh2   = (const float*)d_in[15];
    const float* bh2   = (const float*)d_in[16];
    const float* Wh3   = (const float*)d_in[17];
    const float* bh3   = (const float*)d_in[18];

    float* out = (float*)d_out;
    float* out_logits = out + OUT_LOGITS;
    float* out_probs  = out + OUT_PROBS;
    float* out_ef     = out + OUT_EF;
    float* out_emb    = out + OUT_EMB;
    float* out_focal  = out + OUT_FOCAL;

    const size_t MB = 1024 * 1024;
    char* ws = (char*)d_ws;
    float* c      = (float*)(ws);                    // 8191 floats
    float* flag2  = (float*)(ws + 40960);            // 8192 floats
    float* buf0   = (float*)(ws + 81920);            // 16 MB: ypost -> z2 (fp32)
    float* buf1   = (float*)(ws + 81920 + 16 * MB);  // 16 MB: y -> [a2_bf | emb_bf]
    float* buf2   = (float*)(ws + 81920 + 32 * MB);  // 16 MB: h -> z1_bf
    u16*   wt1    = (u16*)  (ws + 81920 + 48 * MB);  // 512x2048 bf16 = 2 MB
    u16*   wte    = (u16*)  (ws + 81920 + 50 * MB);  // 512x512  bf16 = 0.5 MB
    u16*   wt2    = (u16*)  (ws + 81920 + 50 * MB + 512 * 1024);

    float* ypost  = buf0;
    float* z2f    = buf0;
    float* y      = buf1;
    u16*   a2_bf  = (u16*)buf1;
    u16*   emb_bf = (u16*)((char*)buf1 + 8 * MB);
    float* h      = buf2;
    u16*   z1_bf  = (u16*)buf2;

    focal_kernel<<<dim3(16), dim3(256), 0, stream>>>(cfl, out_focal);
    // weight pre-transpose to bf16 [n][k]
    transpose_bf16<<<dim3(16, 16), dim3(256), 0, stream>>>(W2, wte, HID);
    transpose_bf16<<<dim3(16, 64), dim3(256), 0, stream>>>(Wh1, wt1, 2048);
    transpose_bf16<<<dim3(16, 16), dim3(256), 0, stream>>>(Wh2, wt2, HID);
    // tree recursions in projected 512-d space
    post_kernel<<<dim3(256), dim3(256), 0, stream>>>(ns, ch0, ch1, W1, c, ypost);
    pre_kernel<<<dim3(256), dim3(256), 0, stream>>>(ns, par, cfl, W1, c, ypost, y, flag2);
    // GCN layer 1: h = relu(agg(y) + b1)  (fp32 out)
    gcn_agg_kernel<1, 1, 0><<<dim3(NROWS), dim3(128), 0, stream>>>(y, neigh, b1, h, nullptr);
    // GCN layer 2 aggregation: a2_bf = bf16(agg(h))
    gcn_agg_kernel<0, 0, 1><<<dim3(NROWS), dim3(128), 0, stream>>>(h, neigh, b1, nullptr, a2_bf);
    // emb = a2 @ W2 + b2 -> out_emb (fp32) + emb_bf
    gemm_v3<0, 0><<<dim3(4, 64), dim3(256), 0, stream>>>(a2_bf, wte, b2, nullptr, nullptr,
                                                         nullptr, nullptr, out_emb, emb_bf,
                                                         NROWS, HID);
    // ef rows (fp32, from fp32 emb) -> output
    ef_kernel<<<dim3(NNODES), dim3(256), 0, stream>>>(out_emb, bc, tv, isr, out_ef);
    // z1 = elu(ef @ Wh1 + bh1): A generated on the fly from emb_bf; tail cols in epilogue
    gemm_v3<2, 1><<<dim3(4, 64), dim3(256), 0, stream>>>(emb_bf, wt1, bh1, bc, tv, isr,
                                                         Wh1 + (long)2048 * HID, nullptr,
                                                         z1_bf, NNODES, 2048);
    // z2 = elu(z1 @ Wh2 + bh2) -> fp32
    gemm_v3<2, 0><<<dim3(4, 64), dim3(256), 0, stream>>>(z1_bf, wt2, bh2, nullptr, nullptr,
                                                         nullptr, nullptr, z2f, nullptr,
                                                         NNODES, HID);
    logits_kernel<<<dim3(2048), dim3(256), 0, stream>>>(z2f, Wh3, bh3, out_logits);
    softmax_kernel<<<dim3(1), dim3(1024), 0, stream>>>(out_logits, out_probs);
}

// Round 4
// 389.460 us; speedup vs baseline: 5.6366x; 1.1568x over previous
//
#include <hip/hip_runtime.h>
#include <hip/hip_bf16.h>
#include <math.h>

// Problem constants (fixed by reference)
#define NNODES 8191      // tree nodes, ids 0..8190 (topological: children < parent)
#define ROOT   8190
#define NROWS  8192      // tree nodes + appended focal row
#define FOCALR 8191
#define NLEAF  4096
#define HID    512
#define EDIM   2050

// Output layout (fp32 elements, concat in return order)
#define OUT_LOGITS 0
#define OUT_PROBS  8191
#define OUT_EF     16382
#define OUT_EMB    16807932   // 16382 + 8191*2050
#define OUT_FOCAL  21002236   // + 8192*512

typedef float  f32x4 __attribute__((ext_vector_type(4)));
typedef float  f32x2 __attribute__((ext_vector_type(2)));
typedef float  floatx4 __attribute__((ext_vector_type(4)));
typedef short  short8 __attribute__((ext_vector_type(8)));
typedef unsigned short u16;
typedef unsigned short u16x8 __attribute__((ext_vector_type(8)));
typedef unsigned short u16x4 __attribute__((ext_vector_type(4)));

__device__ __forceinline__ f32x4 ldg4(const float* p) { return *(const f32x4*)p; }
__device__ __forceinline__ f32x2 ldg2(const float* p) { return *(const f32x2*)p; }
__device__ __forceinline__ void stg4(float* p, f32x4 v) { *(f32x4*)p = v; }

// ---- L2-bypass (coherence-point) ops for same-kernel cross-wave handoff ----
__device__ __forceinline__ f32x4 ld4_cv(const float* p) {
    f32x4 v;
    asm volatile("global_load_dwordx4 %0, %1, off sc0 sc1\n\ts_waitcnt vmcnt(0)"
                 : "=v"(v) : "v"(p) : "memory");
    return v;
}
__device__ __forceinline__ void st4_wt(float* p, f32x4 v) {
    asm volatile("global_store_dwordx4 %0, %1, off sc0 sc1" :: "v"(p), "v"(v) : "memory");
}
__device__ __forceinline__ float ld_flag(const float* p) {
    float v;
    asm volatile("global_load_dword %0, %1, off sc0 sc1\n\ts_waitcnt vmcnt(0)"
                 : "=v"(v) : "v"(p) : "memory");
    return v;
}
__device__ __forceinline__ void st_flag_ordered(float* p, float v) {
    asm volatile("s_waitcnt vmcnt(0)\n\tglobal_store_dword %0, %1, off sc0 sc1"
                 :: "v"(p), "v"(v) : "memory");
}

__device__ __forceinline__ u16 f2bf(float x) {
    union { float f; unsigned u; } u; u.f = x;
    unsigned r = u.u + 0x7fffu + ((u.u >> 16) & 1u);   // RNE, finite inputs
    return (u16)(r >> 16);
}
__device__ __forceinline__ float b2f(u16 h) {
    union { unsigned u; float f; } x; x.u = ((unsigned)h) << 16; return x.f;
}

// ---------------- focal one-hot output ----------------
__global__ void focal_kernel(const int* __restrict__ cfl, float* __restrict__ outf) {
    int i = blockIdx.x * 256 + threadIdx.x;
    if (i < NLEAF) outf[i] = (i == cfl[0]) ? 1.0f : 0.0f;
}

// ---------------- weight pre-transpose: W (K x N fp32, N=512) -> WT (N x K bf16) ------
__global__ __launch_bounds__(256) void transpose_bf16(const float* __restrict__ W,
                                                      u16* __restrict__ WT, int K) {
    __shared__ float tile[32][33];
    int tx = threadIdx.x & 31, ty = threadIdx.x >> 5;   // 32 x 8
    int n0 = blockIdx.x * 32, k0 = blockIdx.y * 32;
#pragma unroll
    for (int i = 0; i < 4; i++)
        tile[ty + i * 8][tx] = W[(long)(k0 + ty + i * 8) * HID + n0 + tx];
    __syncthreads();
#pragma unroll
    for (int i = 0; i < 4; i++)
        WT[(long)(n0 + ty + i * 8) * K + k0 + tx] = f2bf(tile[tx][ty + i * 8]);
}

// ---------------- postorder: c[u] and y_post rows (512-d projected belief prop) -------
__global__ __launch_bounds__(256) void post_kernel(const int* __restrict__ ns,
                                                   const int* __restrict__ ch0,
                                                   const int* __restrict__ ch1,
                                                   const float* __restrict__ W1,
                                                   float* c, float* __restrict__ ypost) {
    int gtid = blockIdx.x * 256 + threadIdx.x;
    int wave = gtid >> 6, lane = gtid & 63;
    const int nw = 1024;
    for (int u = wave; u < NNODES; u += nw) {
        if (ns[u] >= 0) continue;  // leaf
        int a = ch0[u], b = ch1[u];
        int nsa = ns[a], nsb = ns[b];
        float ca = 0.0f, cb = 0.0f;
        if (nsa < 0) { do { ca = ld_flag(&c[a]); } while (ca <= 0.0f); }
        if (nsb < 0) { do { cb = ld_flag(&c[b]); } while (cb <= 0.0f); }
        float cu = 1.0f / (3.0f - ca - cb);
        const float* ra = (nsa >= 0) ? (W1 + (long)nsa * HID) : (ypost + (long)a * HID);
        const float* rb = (nsb >= 0) ? (W1 + (long)nsb * HID) : (ypost + (long)b * HID);
        float* dst = ypost + (long)u * HID;
        for (int j = lane * 4; j < HID; j += 256) {
            f32x4 x = (nsa >= 0) ? ldg4(ra + j) : ld4_cv(ra + j);
            f32x4 y = (nsb >= 0) ? ldg4(rb + j) : ld4_cv(rb + j);
            st4_wt(dst + j, (x + y) * cu);
        }
        if (lane == 0) st_flag_ordered(&c[u], cu);
    }
}

// ---------------- preorder: y[u] = y_post[u] + c[u]*y[parent]; leaves/focal = W1 rows --
__global__ __launch_bounds__(256) void pre_kernel(const int* __restrict__ ns,
                                                  const int* __restrict__ par,
                                                  const int* __restrict__ cflp,
                                                  const float* __restrict__ W1,
                                                  const float* __restrict__ c,
                                                  const float* __restrict__ ypost,
                                                  float* __restrict__ y, float* flag2) {
    int gtid = blockIdx.x * 256 + threadIdx.x;
    int wave = gtid >> 6, lane = gtid & 63;
    const int nw = 1024;
    for (int u = (NROWS - 1) - wave; u >= 0; u -= nw) {
        float* dst = y + (long)u * HID;
        if (u == FOCALR) {
            const float* src = W1 + (long)cflp[0] * HID;
            for (int j = lane * 4; j < HID; j += 256) stg4(dst + j, ldg4(src + j));
            continue;
        }
        if (ns[u] >= 0) {
            const float* src = W1 + (long)ns[u] * HID;
            for (int j = lane * 4; j < HID; j += 256) stg4(dst + j, ldg4(src + j));
            continue;
        }
        if (u == ROOT) {
            const float* src = ypost + (long)u * HID;
            for (int j = lane * 4; j < HID; j += 256) st4_wt(dst + j, ldg4(src + j));
        } else {
            int p = par[u];
            while (ld_flag(&flag2[p]) != 1.0f) { }
            float cu = c[u];
            const float* sp = ypost + (long)u * HID;
            const float* pp = y + (long)p * HID;
            for (int j = lane * 4; j < HID; j += 256) {
                f32x4 a = ldg4(sp + j);
                f32x4 b = ld4_cv(pp + j);
                st4_wt(dst + j, a + cu * b);
            }
        }
        if (lane == 0) st_flag_ordered(&flag2[u], 1.0f);
    }
}

// ---------------- GCN neighbor aggregation in 512-d -----------------------------------
template <int RELU, int BIAS, int OBF>
__global__ __launch_bounds__(128) void gcn_agg_kernel(const float* __restrict__ xin,
                                                      const int* __restrict__ neigh,
                                                      const float* __restrict__ bias,
                                                      float* __restrict__ xoutf,
                                                      u16* __restrict__ xoutb) {
    int u = blockIdx.x;
    int t = threadIdx.x;
    int n0 = neigh[u * 3 + 0], n1 = neigh[u * 3 + 1], n2 = neigh[u * 3 + 2];
    float deg = 1.0f + (n0 >= 0) + (n1 >= 0) + (n2 >= 0);
    f32x4 s = ldg4(xin + (long)u * HID + t * 4);
    if (n0 >= 0) s += ldg4(xin + (long)n0 * HID + t * 4);
    if (n1 >= 0) s += ldg4(xin + (long)n1 * HID + t * 4);
    if (n2 >= 0) s += ldg4(xin + (long)n2 * HID + t * 4);
    s *= (1.0f / deg);
    if (BIAS) s += ldg4(bias + t * 4);
    if (RELU) { s.x = fmaxf(s.x, 0.f); s.y = fmaxf(s.y, 0.f); s.z = fmaxf(s.z, 0.f); s.w = fmaxf(s.w, 0.f); }
    if (OBF) {
        u16x4 h; h[0] = f2bf(s.x); h[1] = f2bf(s.y); h[2] = f2bf(s.z); h[3] = f2bf(s.w);
        *(u16x4*)(xoutb + (long)u * HID + t * 4) = h;
    } else {
        stg4(xoutf + (long)u * HID + t * 4, s);
    }
}

// ---------------- bf16 MFMA GEMM v4: software-pipelined, double-buffered --------------
// Tile 128x128, BK=64, 4 waves (2x2). LDS XOR-swizzled, unpadded (2-way conflicts only).
// A: AGEN=0: M x K bf16 row-major. AGEN=1: generated on the fly from emb_bf (8192x512):
//    K=2048 virtual = [hf | ht | |hf-ht| | hf*ht] sections; tail (tv,isr) in epilogue.
// WT: 512 x K bf16 [n][k]. ACT: 0 none, 2 elu. Cf/Cbf nullable fp32/bf16 out (ldc=512).
__device__ __forceinline__ int sw_idx(int row, int kc8) {
    return (row * 8 + (kc8 ^ (row & 7))) * 8;   // u16 index of 16B slot
}

template <int ACT, int AGEN>
__global__ __launch_bounds__(256, 1) void gemm_v4(const u16* __restrict__ Abf,
                                                  const u16* __restrict__ WT,
                                                  const float* __restrict__ bias,
                                                  const int* __restrict__ bc,
                                                  const float* __restrict__ tv,
                                                  const float* __restrict__ isr,
                                                  const float* __restrict__ Wtail,
                                                  float* __restrict__ Cf,
                                                  u16* __restrict__ Cbf,
                                                  int M, int K) {
    __shared__ u16 As[2][128 * 64];
    __shared__ u16 Ws[2][128 * 64];
    const int tid = threadIdx.x, lane = tid & 63;
    const int wm = (tid >> 6) >> 1, wn = (tid >> 6) & 1;
    const int bm = blockIdx.y * 128, bn = blockIdx.x * 128;
    const int kq = lane >> 4, lr = lane & 15;
    const int srow = tid >> 3, schunk = tid & 7;   // staging: 32 rows x 8 chunks
    const int nk = K >> 6;
    floatx4 acc[4][4] = {};

    // hoisted per-row constants for fused-A path
    int btc[4];
    if (AGEN) {
#pragma unroll
        for (int i = 0; i < 4; i++) {
            int gr = bm + srow + i * 32;
            btc[i] = bc[gr < M ? gr : 0];
        }
    }

    // prefetch registers
    u16x8 pf_hf, pf_ht[4], pf_a[4], pf_b[4];

    auto prefetch = [&](int kk) {
        if (AGEN) {
            int sec = kk >> 3;
            int cb = (kk & 7) * 64 + schunk * 8;
            pf_hf = *(const u16x8*)(Abf + (long)FOCALR * HID + cb);
            if (sec != 0) {
#pragma unroll
                for (int i = 0; i < 4; i++)
                    pf_ht[i] = *(const u16x8*)(Abf + (long)btc[i] * HID + cb);
            }
        } else {
            long kof = (long)(kk * 64 + schunk * 8);
#pragma unroll
            for (int i = 0; i < 4; i++)
                pf_a[i] = *(const u16x8*)(Abf + (long)(bm + srow + i * 32) * K + kof);
        }
#pragma unroll
        for (int i = 0; i < 4; i++)
            pf_b[i] = *(const u16x8*)(WT + (long)(bn + srow + i * 32) * K + kk * 64 + schunk * 8);
    };

    auto commit = [&](int kk, int buf) {
        if (AGEN) {
            int sec = kk >> 3;
#pragma unroll
            for (int i = 0; i < 4; i++) {
                u16x8 v;
                if (sec == 0) v = pf_hf;
                else if (sec == 1) v = pf_ht[i];
                else if (sec == 2) {
#pragma unroll
                    for (int q = 0; q < 8; q++) v[q] = f2bf(fabsf(b2f(pf_hf[q]) - b2f(pf_ht[i][q])));
                } else {
#pragma unroll
                    for (int q = 0; q < 8; q++) v[q] = f2bf(b2f(pf_hf[q]) * b2f(pf_ht[i][q]));
                }
                *(u16x8*)&As[buf][sw_idx(srow + i * 32, schunk)] = v;
            }
        } else {
#pragma unroll
            for (int i = 0; i < 4; i++)
                *(u16x8*)&As[buf][sw_idx(srow + i * 32, schunk)] = pf_a[i];
        }
#pragma unroll
        for (int i = 0; i < 4; i++)
            *(u16x8*)&Ws[buf][sw_idx(srow + i * 32, schunk)] = pf_b[i];
    };

    // prologue: stage chunk 0 into buffer 0
    prefetch(0);
    commit(0, 0);
    __syncthreads();

    for (int kk = 0; kk < nk; kk++) {
        int cur = kk & 1;
        bool more = (kk + 1) < nk;
        if (more) prefetch(kk + 1);     // global loads in flight during MFMA below
        // ---- compute chunk kk ----
#pragma unroll
        for (int kc = 0; kc < 2; kc++) {
            short8 af[4], bf8[4];
#pragma unroll
            for (int t2 = 0; t2 < 4; t2++) {
                af[t2]  = *(short8*)&As[cur][sw_idx(wm * 64 + t2 * 16 + lr, kc * 4 + kq)];
                bf8[t2] = *(short8*)&Ws[cur][sw_idx(wn * 64 + t2 * 16 + lr, kc * 4 + kq)];
            }
#pragma unroll
            for (int i2 = 0; i2 < 4; i2++)
#pragma unroll
                for (int j = 0; j < 4; j++)
                    acc[i2][j] = __builtin_amdgcn_mfma_f32_16x16x32_bf16(af[i2], bf8[j], acc[i2][j], 0, 0, 0);
        }
        if (more) {
            __syncthreads();            // all waves done reading buf[cur^1] (iter kk-1)
            commit(kk + 1, cur ^ 1);    // convert (waits loads) + ds_write
            __syncthreads();            // writes visible before next iter's reads
        }
    }

    // ---- epilogue: row=(lane>>4)*4+reg, col=lane&15 ----
#pragma unroll
    for (int i = 0; i < 4; i++) {
        int row0 = bm + wm * 64 + i * 16 + kq * 4;
#pragma unroll
        for (int j = 0; j < 4; j++) {
            int col = bn + wn * 64 + j * 16 + lr;
            float bv = bias[col];
            float t0 = 0.f, t1 = 0.f;
            if (AGEN) { t0 = Wtail[col]; t1 = Wtail[512 + col]; }
#pragma unroll
            for (int r = 0; r < 4; r++) {
                int gr = row0 + r;
                if (gr < M) {
                    float v = acc[i][j][r] + bv;
                    if (AGEN) v += tv[gr] * t0 + isr[gr] * t1;
                    if (ACT == 2) v = (v > 0.0f) ? v : (expf(v) - 1.0f);
                    if (Cf)  Cf[(long)gr * HID + col] = v;
                    if (Cbf) Cbf[(long)gr * HID + col] = f2bf(v);
                }
            }
        }
    }
}

// ---------------- ef rows: [hf | ht | |hf-ht| | hf*ht | t_norm | is_root] -------------
__global__ __launch_bounds__(256) void ef_kernel(const float* __restrict__ emb,
                                                 const int* __restrict__ bc,
                                                 const float* __restrict__ tv,
                                                 const float* __restrict__ isr,
                                                 float* __restrict__ ef) {
    int u = blockIdx.x;
    int t = threadIdx.x;
    const float* hf = emb + (long)FOCALR * HID;
    const float* ht = emb + (long)bc[u] * HID;
    f32x2 f = ldg2(hf + 2 * t);
    f32x2 h = ldg2(ht + 2 * t);
    float* row = ef + (long)u * EDIM;
    *(f32x2*)(row + 2 * t) = f;
    *(f32x2*)(row + 512 + 2 * t) = h;
    f32x2 d; d[0] = fabsf(f[0] - h[0]); d[1] = fabsf(f[1] - h[1]);
    *(f32x2*)(row + 1024 + 2 * t) = d;
    f32x2 p; p[0] = f[0] * h[0]; p[1] = f[1] * h[1];
    *(f32x2*)(row + 1536 + 2 * t) = p;
    if (t == 0) {
        row[2048] = tv[u];
        row[2049] = isr[u];
    }
}

// ---------------- logits: z2 (8191x512) @ W_h3 (512x1) + b ----------------------------
__global__ __launch_bounds__(256) void logits_kernel(const float* __restrict__ z2,
                                                     const float* __restrict__ W3,
                                                     const float* __restrict__ b3,
                                                     float* __restrict__ out) {
    int wv = threadIdx.x >> 6, lane = threadIdx.x & 63;
    int row = blockIdx.x * 4 + wv;
    if (row >= NNODES) return;
    const float* zr = z2 + (long)row * HID;
    float s = 0.0f;
#pragma unroll
    for (int j = 0; j < 8; j++) s += zr[lane * 8 + j] * W3[lane * 8 + j];
    for (int o = 32; o; o >>= 1) s += __shfl_down(s, o);
    if (lane == 0) out[row] = s + b3[0];
}

// ---------------- softmax over 8191 logits (single block) -----------------------------
__global__ __launch_bounds__(1024) void softmax_kernel(const float* __restrict__ lg,
                                                       float* __restrict__ probs) {
    __shared__ float red[16];
    __shared__ float gmax_s, gsum_s;
    int t = threadIdx.x, wid = t >> 6, lane = t & 63;
    float m = -3.4e38f;
    for (int i = t; i < NNODES; i += 1024) m = fmaxf(m, lg[i]);
    for (int o = 32; o; o >>= 1) m = fmaxf(m, __shfl_down(m, o));
    if (lane == 0) red[wid] = m;
    __syncthreads();
    if (t == 0) {
        float g = red[0];
        for (int i = 1; i < 16; i++) g = fmaxf(g, red[i]);
        gmax_s = g;
    }
    __syncthreads();
    float gmax = gmax_s;
    float s = 0.0f;
    for (int i = t; i < NNODES; i += 1024) s += expf(lg[i] - gmax);
    for (int o = 32; o; o >>= 1) s += __shfl_down(s, o);
    if (lane == 0) red[wid] = s;
    __syncthreads();
    if (t == 0) {
        float g = 0.0f;
        for (int i = 0; i < 16; i++) g += red[i];
        gsum_s = g;
    }
    __syncthreads();
    float inv = 1.0f / gsum_s;
    for (int i = t; i < NNODES; i += 1024) probs[i] = expf(lg[i] - gmax) * inv;
}

extern "C" void kernel_launch(void* const* d_in, const int* in_sizes, int n_in,
                              void* d_out, int out_size, void* d_ws, size_t ws_size,
                              hipStream_t stream) {
    const int*   ns    = (const int*)d_in[0];
    const int*   ch0   = (const int*)d_in[1];
    const int*   ch1   = (const int*)d_in[2];
    const int*   par   = (const int*)d_in[3];
    const int*   neigh = (const int*)d_in[4];
    const int*   bc    = (const int*)d_in[5];
    const int*   cfl   = (const int*)d_in[6];
    const float* tv    = (const float*)d_in[7];
    const float* isr   = (const float*)d_in[8];
    const float* W1    = (const float*)d_in[9];
    const float* b1    = (const float*)d_in[10];
    const float* W2    = (const float*)d_in[11];
    const float* b2    = (const float*)d_in[12];
    const float* Wh1   = (const float*)d_in[13];
    const float* bh1   = (const float*)d_in[14];
    const float* Wh2   = (const float*)d_in[15];
    const float* bh2   = (const float*)d_in[16];
    const float* Wh3   = (const float*)d_in[17];
    const float* bh3   = (const float*)d_in[18];

    float* out = (float*)d_out;
    float* out_logits = out + OUT_LOGITS;
    float* out_probs  = out + OUT_PROBS;
    float* out_ef     = out + OUT_EF;
    float* out_emb    = out + OUT_EMB;
    float* out_focal  = out + OUT_FOCAL;

    const size_t MB = 1024 * 1024;
    char* ws = (char*)d_ws;
    float* c      = (float*)(ws);                    // 8191 floats
    float* flag2  = (float*)(ws + 40960);            // 8192 floats
    float* buf0   = (float*)(ws + 81920);            // 16 MB: ypost -> z2 (fp32)
    float* buf1   = (float*)(ws + 81920 + 16 * MB);  // 16 MB: y -> [a2_bf | emb_bf]
    float* buf2   = (float*)(ws + 81920 + 32 * MB);  // 16 MB: h -> z1_bf
    u16*   wt1    = (u16*)  (ws + 81920 + 48 * MB);  // 512x2048 bf16 = 2 MB
    u16*   wte    = (u16*)  (ws + 81920 + 50 * MB);  // 512x512  bf16 = 0.5 MB
    u16*   wt2    = (u16*)  (ws + 81920 + 50 * MB + 512 * 1024);

    float* ypost  = buf0;
    float* z2f    = buf0;
    float* y      = buf1;
    u16*   a2_bf  = (u16*)buf1;
    u16*   emb_bf = (u16*)((char*)buf1 + 8 * MB);
    float* h      = buf2;
    u16*   z1_bf  = (u16*)buf2;

    focal_kernel<<<dim3(16), dim3(256), 0, stream>>>(cfl, out_focal);
    // weight pre-transpose to bf16 [n][k]
    transpose_bf16<<<dim3(16, 16), dim3(256), 0, stream>>>(W2, wte, HID);
    transpose_bf16<<<dim3(16, 64), dim3(256), 0, stream>>>(Wh1, wt1, 2048);
    transpose_bf16<<<dim3(16, 16), dim3(256), 0, stream>>>(Wh2, wt2, HID);
    // tree recursions in projected 512-d space
    post_kernel<<<dim3(256), dim3(256), 0, stream>>>(ns, ch0, ch1, W1, c, ypost);
    pre_kernel<<<dim3(256), dim3(256), 0, stream>>>(ns, par, cfl, W1, c, ypost, y, flag2);
    // GCN layer 1: h = relu(agg(y) + b1)  (fp32 out)
    gcn_agg_kernel<1, 1, 0><<<dim3(NROWS), dim3(128), 0, stream>>>(y, neigh, b1, h, nullptr);
    // GCN layer 2 aggregation: a2_bf = bf16(agg(h))
    gcn_agg_kernel<0, 0, 1><<<dim3(NROWS), dim3(128), 0, stream>>>(h, neigh, b1, nullptr, a2_bf);
    // emb = a2 @ W2 + b2 -> out_emb (fp32) + emb_bf
    gemm_v4<0, 0><<<dim3(4, 64), dim3(256), 0, stream>>>(a2_bf, wte, b2, nullptr, nullptr,
                                                         nullptr, nullptr, out_emb, emb_bf,
                                                         NROWS, HID);
    // ef rows (fp32, from fp32 emb) -> output
    ef_kernel<<<dim3(NNODES), dim3(256), 0, stream>>>(out_emb, bc, tv, isr, out_ef);
    // z1 = elu(ef @ Wh1 + bh1): A generated on the fly from emb_bf; tail cols in epilogue
    gemm_v4<2, 1><<<dim3(4, 64), dim3(256), 0, stream>>>(emb_bf, wt1, bh1, bc, tv, isr,
                                                         Wh1 + (long)2048 * HID, nullptr,
                                                         z1_bf, NNODES, 2048);
    // z2 = elu(z1 @ Wh2 + bh2) -> fp32
    gemm_v4<2, 0><<<dim3(4, 64), dim3(256), 0, stream>>>(z1_bf, wt2, bh2, nullptr, nullptr,
                                                         nullptr, nullptr, z2f, nullptr,
                                                         NNODES, HID);
    logits_kernel<<<dim3(2048), dim3(256), 0, stream>>>(z2f, Wh3, bh3, out_logits);
    softmax_kernel<<<dim3(1), dim3(1024), 0, stream>>>(out_logits, out_probs);
}

// Round 5
// 384.154 us; speedup vs baseline: 5.7145x; 1.0138x over previous
//
#include <hip/hip_runtime.h>
#include <hip/hip_bf16.h>
#include <math.h>

// Problem constants (fixed by reference)
#define NNODES 8191      // tree nodes, ids 0..8190 (topological: children < parent)
#define ROOT   8190
#define NROWS  8192      // tree nodes + appended focal row
#define FOCALR 8191
#define NLEAF  4096
#define HID    512
#define EDIM   2050

// Output layout (fp32 elements, concat in return order)
#define OUT_LOGITS 0
#define OUT_PROBS  8191
#define OUT_EF     16382
#define OUT_EMB    16807932   // 16382 + 8191*2050
#define OUT_FOCAL  21002236   // + 8192*512

typedef float  f32x4 __attribute__((ext_vector_type(4)));
typedef float  f32x2 __attribute__((ext_vector_type(2)));
typedef float  floatx4 __attribute__((ext_vector_type(4)));
typedef short  short8 __attribute__((ext_vector_type(8)));
typedef unsigned short u16;
typedef unsigned short u16x8 __attribute__((ext_vector_type(8)));
typedef unsigned short u16x4 __attribute__((ext_vector_type(4)));

__device__ __forceinline__ f32x4 ldg4(const float* p) { return *(const f32x4*)p; }
__device__ __forceinline__ f32x2 ldg2(const float* p) { return *(const f32x2*)p; }
__device__ __forceinline__ void stg4(float* p, f32x4 v) { *(f32x4*)p = v; }

// ---- L2-bypass (coherence-point) ops for same-kernel cross-wave handoff ----
__device__ __forceinline__ f32x4 ld4_cv(const float* p) {
    f32x4 v;
    asm volatile("global_load_dwordx4 %0, %1, off sc0 sc1\n\ts_waitcnt vmcnt(0)"
                 : "=v"(v) : "v"(p) : "memory");
    return v;
}
__device__ __forceinline__ void st4_wt(float* p, f32x4 v) {
    asm volatile("global_store_dwordx4 %0, %1, off sc0 sc1" :: "v"(p), "v"(v) : "memory");
}
__device__ __forceinline__ float ld_flag(const float* p) {
    float v;
    asm volatile("global_load_dword %0, %1, off sc0 sc1\n\ts_waitcnt vmcnt(0)"
                 : "=v"(v) : "v"(p) : "memory");
    return v;
}
__device__ __forceinline__ void st_flag_ordered(float* p, float v) {
    asm volatile("s_waitcnt vmcnt(0)\n\tglobal_store_dword %0, %1, off sc0 sc1"
                 :: "v"(p), "v"(v) : "memory");
}

__device__ __forceinline__ u16 f2bf(float x) {
    union { float f; unsigned u; } u; u.f = x;
    unsigned r = u.u + 0x7fffu + ((u.u >> 16) & 1u);   // RNE, finite inputs
    return (u16)(r >> 16);
}
__device__ __forceinline__ float b2f(u16 h) {
    union { unsigned u; float f; } x; x.u = ((unsigned)h) << 16; return x.f;
}

// ---------------- focal one-hot output ----------------
__global__ void focal_kernel(const int* __restrict__ cfl, float* __restrict__ outf) {
    int i = blockIdx.x * 256 + threadIdx.x;
    if (i < NLEAF) outf[i] = (i == cfl[0]) ? 1.0f : 0.0f;
}

// ---------------- fused static transposes: 3 sections of (512 x 512 fp32) -> bf16 [n][k]
// sec0: W2 -> wte (ld 512); sec1: Wh2 -> wt2 (ld 512); sec2: Wh1 rows 1024..1535 (W_C)
// -> WTz1 cols 512..1023 (ld 1024).
__global__ __launch_bounds__(256) void transpose3_kernel(const float* __restrict__ W2,
                                                         const float* __restrict__ Wh2,
                                                         const float* __restrict__ Wh1,
                                                         u16* __restrict__ wte,
                                                         u16* __restrict__ wt2,
                                                         u16* __restrict__ WTz1) {
    __shared__ float tile[32][33];
    int sec = blockIdx.y >> 4, kt = blockIdx.y & 15;
    int tx = threadIdx.x & 31, ty = threadIdx.x >> 5;   // 32 x 8
    int n0 = blockIdx.x * 32, k0 = kt * 32;
    const float* src = (sec == 0) ? W2 : (sec == 1) ? Wh2 : (Wh1 + (long)1024 * HID);
    u16* dst = (sec == 0) ? wte : (sec == 1) ? wt2 : WTz1;
    int ld = (sec == 2) ? 1024 : 512;
    int koff = (sec == 2) ? 512 : 0;
#pragma unroll
    for (int i = 0; i < 4; i++)
        tile[ty + i * 8][tx] = src[(long)(k0 + ty + i * 8) * HID + n0 + tx];
    __syncthreads();
#pragma unroll
    for (int i = 0; i < 4; i++)
        dst[(long)(n0 + ty + i * 8) * ld + koff + k0 + tx] = f2bf(tile[tx][ty + i * 8]);
}

// ---------------- z1 weight fold (after emb): WTz1[n][k] (k<512) = W_B + hf[k]*W_D ----
__global__ __launch_bounds__(256) void zprep_kernel(const float* __restrict__ Wh1,
                                                    const float* __restrict__ emb,
                                                    u16* __restrict__ WTz1) {
    __shared__ float tB[32][33];
    __shared__ float tD[32][33];
    const float* hf = emb + (long)FOCALR * HID;
    int tx = threadIdx.x & 31, ty = threadIdx.x >> 5;
    int n0 = blockIdx.x * 32, k0 = blockIdx.y * 32;
#pragma unroll
    for (int i = 0; i < 4; i++) {
        tB[ty + i * 8][tx] = Wh1[(long)(512 + k0 + ty + i * 8) * HID + n0 + tx];
        tD[ty + i * 8][tx] = Wh1[(long)(1536 + k0 + ty + i * 8) * HID + n0 + tx];
    }
    __syncthreads();
#pragma unroll
    for (int i = 0; i < 4; i++) {
        float hfk = hf[k0 + tx];
        WTz1[(long)(n0 + ty + i * 8) * 1024 + k0 + tx] =
            f2bf(tB[tx][ty + i * 8] + hfk * tD[tx][ty + i * 8]);
    }
}

// ---------------- bias fold: bprime[n] = bh1[n] + sum_k hf[k] * Wh1[k][n] -------------
__global__ __launch_bounds__(256) void bvec_kernel(const float* __restrict__ Wh1,
                                                   const float* __restrict__ bh1,
                                                   const float* __restrict__ emb,
                                                   float* __restrict__ bprime) {
    const float* hf = emb + (long)FOCALR * HID;
    int n = blockIdx.x * 256 + threadIdx.x;
    float s = bh1[n];
#pragma unroll 8
    for (int k = 0; k < HID; k++) s += hf[k] * Wh1[(long)k * HID + n];
    bprime[n] = s;
}

// ---------------- postorder: c[u] and y_post rows (512-d projected belief prop) -------
__global__ __launch_bounds__(256) void post_kernel(const int* __restrict__ ns,
                                                   const int* __restrict__ ch0,
                                                   const int* __restrict__ ch1,
                                                   const float* __restrict__ W1,
                                                   float* c, float* __restrict__ ypost) {
    int gtid = blockIdx.x * 256 + threadIdx.x;
    int wave = gtid >> 6, lane = gtid & 63;
    const int nw = 1024;
    for (int u = NLEAF + wave; u < NNODES; u += nw) {   // internal nodes only
        int a = ch0[u], b = ch1[u];
        int nsa = ns[a], nsb = ns[b];
        float ca = 0.0f, cb = 0.0f;
        if (nsa < 0) { do { ca = ld_flag(&c[a]); } while (ca <= 0.0f); }
        if (nsb < 0) { do { cb = ld_flag(&c[b]); } while (cb <= 0.0f); }
        float cu = 1.0f / (3.0f - ca - cb);
        const float* ra = (nsa >= 0) ? (W1 + (long)nsa * HID) : (ypost + (long)a * HID);
        const float* rb = (nsb >= 0) ? (W1 + (long)nsb * HID) : (ypost + (long)b * HID);
        float* dst = ypost + (long)u * HID;
        for (int j = lane * 4; j < HID; j += 256) {
            f32x4 x = (nsa >= 0) ? ldg4(ra + j) : ld4_cv(ra + j);
            f32x4 y = (nsb >= 0) ? ldg4(rb + j) : ld4_cv(rb + j);
            st4_wt(dst + j, (x + y) * cu);
        }
        if (lane == 0) st_flag_ordered(&c[u], cu);
    }
}

// ---------------- preorder: internal nodes only; y[u] = y_post[u] + c[u]*y[parent] ----
__global__ __launch_bounds__(256) void pre_kernel(const int* __restrict__ par,
                                                  const float* __restrict__ c,
                                                  const float* __restrict__ ypost,
                                                  float* __restrict__ y, float* flag2) {
    int gtid = blockIdx.x * 256 + threadIdx.x;
    int wave = gtid >> 6, lane = gtid & 63;
    const int nw = 1024;
    for (int u = ROOT - wave; u >= NLEAF; u -= nw) {
        float* dst = y + (long)u * HID;
        if (u == ROOT) {
            const float* src = ypost + (long)u * HID;
            for (int j = lane * 4; j < HID; j += 256) st4_wt(dst + j, ldg4(src + j));
        } else {
            int p = par[u];
            while (ld_flag(&flag2[p]) != 1.0f) { }
            float cu = c[u];
            const float* sp = ypost + (long)u * HID;
            const float* pp = y + (long)p * HID;
            for (int j = lane * 4; j < HID; j += 256) {
                f32x4 a = ldg4(sp + j);
                f32x4 b = ld4_cv(pp + j);
                st4_wt(dst + j, a + cu * b);
            }
        }
        if (lane == 0) st_flag_ordered(&flag2[u], 1.0f);
    }
}

// ---------------- GCN neighbor aggregation in 512-d -----------------------------------
// REDIR=1: leaf/focal rows read directly from W1 (y rows only exist for internal nodes)
template <int RELU, int BIAS, int OBF, int REDIR>
__global__ __launch_bounds__(128) void gcn_agg_kernel(const float* __restrict__ xin,
                                                      const int* __restrict__ neigh,
                                                      const float* __restrict__ bias,
                                                      const int* __restrict__ ns,
                                                      const int* __restrict__ cfl,
                                                      const float* __restrict__ W1,
                                                      float* __restrict__ xoutf,
                                                      u16* __restrict__ xoutb) {
    int u = blockIdx.x;
    int t = threadIdx.x;
    int n0 = neigh[u * 3 + 0], n1 = neigh[u * 3 + 1], n2 = neigh[u * 3 + 2];
    float deg = 1.0f + (n0 >= 0) + (n1 >= 0) + (n2 >= 0);
    auto rowp = [&](int v) -> const float* {
        if (!REDIR) return xin + (long)v * HID;
        if (v == FOCALR) return W1 + (long)cfl[0] * HID;
        int nv = ns[v];
        return (nv >= 0) ? (W1 + (long)nv * HID) : (xin + (long)v * HID);
    };
    f32x4 s = ldg4(rowp(u) + t * 4);
    if (n0 >= 0) s += ldg4(rowp(n0) + t * 4);
    if (n1 >= 0) s += ldg4(rowp(n1) + t * 4);
    if (n2 >= 0) s += ldg4(rowp(n2) + t * 4);
    s *= (1.0f / deg);
    if (BIAS) s += ldg4(bias + t * 4);
    if (RELU) { s.x = fmaxf(s.x, 0.f); s.y = fmaxf(s.y, 0.f); s.z = fmaxf(s.z, 0.f); s.w = fmaxf(s.w, 0.f); }
    if (OBF) {
        u16x4 h; h[0] = f2bf(s.x); h[1] = f2bf(s.y); h[2] = f2bf(s.z); h[3] = f2bf(s.w);
        *(u16x4*)(xoutb + (long)u * HID + t * 4) = h;
    } else {
        stg4(xoutf + (long)u * HID + t * 4, s);
    }
}

// ---------------- bf16 MFMA GEMM v5: 64x128 tile, dbuf pipeline, 512-block grid -------
// A: AGEN=0: M x K bf16 row-major. AGEN=1 (folded z1): K=1024 virtual = [ht | |hf-ht|]
//    from emb_bf rows bc[r] and hf row; tail (tv,isr) in epilogue.
// WT: 512 x K bf16 [n][k]. ACT: 0 none, 2 elu. Cf/Cbf nullable fp32/bf16 out (ldc=512).
__device__ __forceinline__ int sw_idx(int row, int kc8) {
    return (row * 8 + (kc8 ^ (row & 7))) * 8;   // u16 index of 16B slot
}

template <int ACT, int AGEN>
__global__ __launch_bounds__(256, 3) void gemm_v5(const u16* __restrict__ Abf,
                                                  const u16* __restrict__ WT,
                                                  const float* __restrict__ bias,
                                                  const int* __restrict__ bc,
                                                  const float* __restrict__ tv,
                                                  const float* __restrict__ isr,
                                                  const float* __restrict__ Wtail,
                                                  float* __restrict__ Cf,
                                                  u16* __restrict__ Cbf,
                                                  int M, int K) {
    __shared__ u16 As[2][64 * 64];
    __shared__ u16 Ws[2][128 * 64];
    const int tid = threadIdx.x, lane = tid & 63;
    const int wm = (tid >> 6) >> 1, wn = (tid >> 6) & 1;
    const int bm = blockIdx.y * 64, bn = blockIdx.x * 128;
    const int kq = lane >> 4, lr = lane & 15;
    const int srow = tid >> 3, schunk = tid & 7;   // staging: 32 rows x 8 chunks
    const int nk = K >> 6;
    floatx4 acc[2][4] = {};

    int btc[2];
    if (AGEN) {
#pragma unroll
        for (int i = 0; i < 2; i++) {
            int gr = bm + srow + i * 32;
            btc[i] = bc[gr < M ? gr : 0];
        }
    }

    u16x8 pf_hf, pf_a[2], pf_b[4];

    auto prefetch = [&](int kk) {
        if (AGEN) {
            int cb = (kk & 7) * 64 + schunk * 8;
            pf_hf = *(const u16x8*)(Abf + (long)FOCALR * HID + cb);
#pragma unroll
            for (int i = 0; i < 2; i++)
                pf_a[i] = *(const u16x8*)(Abf + (long)btc[i] * HID + cb);
        } else {
            long kof = (long)(kk * 64 + schunk * 8);
#pragma unroll
            for (int i = 0; i < 2; i++) {
                int gr = bm + srow + i * 32;
                if (gr < M) pf_a[i] = *(const u16x8*)(Abf + (long)gr * K + kof);
                else        pf_a[i] = (u16x8){0,0,0,0,0,0,0,0};
            }
        }
#pragma unroll
        for (int i = 0; i < 4; i++)
            pf_b[i] = *(const u16x8*)(WT + (long)(bn + srow + i * 32) * K + kk * 64 + schunk * 8);
    };

    auto commit = [&](int kk, int buf) {
        if (AGEN) {
            int sec = kk >> 3;
#pragma unroll
            for (int i = 0; i < 2; i++) {
                u16x8 v;
                if (sec == 0) v = pf_a[i];
                else {
#pragma unroll
                    for (int q = 0; q < 8; q++) v[q] = f2bf(fabsf(b2f(pf_hf[q]) - b2f(pf_a[i][q])));
                }
                if (bm + srow + i * 32 >= M) v = (u16x8){0,0,0,0,0,0,0,0};
                *(u16x8*)&As[buf][sw_idx(srow + i * 32, schunk)] = v;
            }
        } else {
#pragma unroll
            for (int i = 0; i < 2; i++)
                *(u16x8*)&As[buf][sw_idx(srow + i * 32, schunk)] = pf_a[i];
        }
#pragma unroll
        for (int i = 0; i < 4; i++)
            *(u16x8*)&Ws[buf][sw_idx(srow + i * 32, schunk)] = pf_b[i];
    };

    prefetch(0);
    commit(0, 0);
    __syncthreads();

    for (int kk = 0; kk < nk; kk++) {
        int cur = kk & 1;
        bool more = (kk + 1) < nk;
        if (more) prefetch(kk + 1);
#pragma unroll
        for (int kc = 0; kc < 2; kc++) {
            short8 af[2], bf8[4];
#pragma unroll
            for (int t2 = 0; t2 < 2; t2++)
                af[t2]  = *(short8*)&As[cur][sw_idx(wm * 32 + t2 * 16 + lr, kc * 4 + kq)];
#pragma unroll
            for (int t2 = 0; t2 < 4; t2++)
                bf8[t2] = *(short8*)&Ws[cur][sw_idx(wn * 64 + t2 * 16 + lr, kc * 4 + kq)];
#pragma unroll
            for (int i2 = 0; i2 < 2; i2++)
#pragma unroll
                for (int j = 0; j < 4; j++)
                    acc[i2][j] = __builtin_amdgcn_mfma_f32_16x16x32_bf16(af[i2], bf8[j], acc[i2][j], 0, 0, 0);
        }
        if (more) {
            __syncthreads();
            commit(kk + 1, cur ^ 1);
            __syncthreads();
        }
    }

    // ---- epilogue: row=(lane>>4)*4+reg, col=lane&15 ----
#pragma unroll
    for (int i = 0; i < 2; i++) {
        int row0 = bm + wm * 32 + i * 16 + kq * 4;
#pragma unroll
        for (int j = 0; j < 4; j++) {
            int col = bn + wn * 64 + j * 16 + lr;
            float bv = bias[col];
            float t0 = 0.f, t1 = 0.f;
            if (AGEN) { t0 = Wtail[col]; t1 = Wtail[512 + col]; }
#pragma unroll
            for (int r = 0; r < 4; r++) {
                int gr = row0 + r;
                if (gr < M) {
                    float v = acc[i][j][r] + bv;
                    if (AGEN) v += tv[gr] * t0 + isr[gr] * t1;
                    if (ACT == 2) v = (v > 0.0f) ? v : (expf(v) - 1.0f);
                    if (Cf)  Cf[(long)gr * HID + col] = v;
                    if (Cbf) Cbf[(long)gr * HID + col] = f2bf(v);
                }
            }
        }
    }
}

// ---------------- ef rows: [hf | ht | |hf-ht| | hf*ht | t_norm | is_root] -------------
__global__ __launch_bounds__(256) void ef_kernel(const float* __restrict__ emb,
                                                 const int* __restrict__ bc,
                                                 const float* __restrict__ tv,
                                                 const float* __restrict__ isr,
                                                 float* __restrict__ ef) {
    int u = blockIdx.x;
    int t = threadIdx.x;
    const float* hf = emb + (long)FOCALR * HID;
    const float* ht = emb + (long)bc[u] * HID;
    f32x2 f = ldg2(hf + 2 * t);
    f32x2 h = ldg2(ht + 2 * t);
    float* row = ef + (long)u * EDIM;
    *(f32x2*)(row + 2 * t) = f;
    *(f32x2*)(row + 512 + 2 * t) = h;
    f32x2 d; d[0] = fabsf(f[0] - h[0]); d[1] = fabsf(f[1] - h[1]);
    *(f32x2*)(row + 1024 + 2 * t) = d;
    f32x2 p; p[0] = f[0] * h[0]; p[1] = f[1] * h[1];
    *(f32x2*)(row + 1536 + 2 * t) = p;
    if (t == 0) {
        row[2048] = tv[u];
        row[2049] = isr[u];
    }
}

// ---------------- logits: z2 (8191x512) @ W_h3 (512x1) + b ----------------------------
__global__ __launch_bounds__(256) void logits_kernel(const float* __restrict__ z2,
                                                     const float* __restrict__ W3,
                                                     const float* __restrict__ b3,
                                                     float* __restrict__ out) {
    int wv = threadIdx.x >> 6, lane = threadIdx.x & 63;
    int row = blockIdx.x * 4 + wv;
    if (row >= NNODES) return;
    const float* zr = z2 + (long)row * HID;
    float s = 0.0f;
#pragma unroll
    for (int j = 0; j < 8; j++) s += zr[lane * 8 + j] * W3[lane * 8 + j];
    for (int o = 32; o; o >>= 1) s += __shfl_down(s, o);
    if (lane == 0) out[row] = s + b3[0];
}

// ---------------- softmax over 8191 logits (single block) -----------------------------
__global__ __launch_bounds__(1024) void softmax_kernel(const float* __restrict__ lg,
                                                       float* __restrict__ probs) {
    __shared__ float red[16];
    __shared__ float gmax_s, gsum_s;
    int t = threadIdx.x, wid = t >> 6, lane = t & 63;
    float m = -3.4e38f;
    for (int i = t; i < NNODES; i += 1024) m = fmaxf(m, lg[i]);
    for (int o = 32; o; o >>= 1) m = fmaxf(m, __shfl_down(m, o));
    if (lane == 0) red[wid] = m;
    __syncthreads();
    if (t == 0) {
        float g = red[0];
        for (int i = 1; i < 16; i++) g = fmaxf(g, red[i]);
        gmax_s = g;
    }
    __syncthreads();
    float gmax = gmax_s;
    float s = 0.0f;
    for (int i = t; i < NNODES; i += 1024) s += expf(lg[i] - gmax);
    for (int o = 32; o; o >>= 1) s += __shfl_down(s, o);
    if (lane == 0) red[wid] = s;
    __syncthreads();
    if (t == 0) {
        float g = 0.0f;
        for (int i = 0; i < 16; i++) g += red[i];
        gsum_s = g;
    }
    __syncthreads();
    float inv = 1.0f / gsum_s;
    for (int i = t; i < NNODES; i += 1024) probs[i] = expf(lg[i] - gmax) * inv;
}

extern "C" void kernel_launch(void* const* d_in, const int* in_sizes, int n_in,
                              void* d_out, int out_size, void* d_ws, size_t ws_size,
                              hipStream_t stream) {
    const int*   ns    = (const int*)d_in[0];
    const int*   ch0   = (const int*)d_in[1];
    const int*   ch1   = (const int*)d_in[2];
    const int*   par   = (const int*)d_in[3];
    const int*   neigh = (const int*)d_in[4];
    const int*   bc    = (const int*)d_in[5];
    const int*   cfl   = (const int*)d_in[6];
    const float* tv    = (const float*)d_in[7];
    const float* isr   = (const float*)d_in[8];
    const float* W1    = (const float*)d_in[9];
    const float* b1    = (const float*)d_in[10];
    const float* W2    = (const float*)d_in[11];
    const float* b2    = (const float*)d_in[12];
    const float* Wh1   = (const float*)d_in[13];
    const float* bh1   = (const float*)d_in[14];
    const float* Wh2   = (const float*)d_in[15];
    const float* bh2   = (const float*)d_in[16];
    const float* Wh3   = (const float*)d_in[17];
    const float* bh3   = (const float*)d_in[18];

    float* out = (float*)d_out;
    float* out_logits = out + OUT_LOGITS;
    float* out_probs  = out + OUT_PROBS;
    float* out_ef     = out + OUT_EF;
    float* out_emb    = out + OUT_EMB;
    float* out_focal  = out + OUT_FOCAL;

    const size_t MB = 1024 * 1024;
    char* ws = (char*)d_ws;
    float* c      = (float*)(ws);                    // 8191 floats
    float* flag2  = (float*)(ws + 40960);            // 8192 floats
    float* buf0   = (float*)(ws + 81920);            // 16 MB: ypost -> z2 (fp32)
    float* buf1   = (float*)(ws + 81920 + 16 * MB);  // 16 MB: y -> [a2_bf | emb_bf]
    float* buf2   = (float*)(ws + 81920 + 32 * MB);  // 16 MB: h -> z1_bf
    u16*   wte    = (u16*)  (ws + 81920 + 48 * MB);          // 512x512  bf16 = 0.5 MB
    u16*   wt2    = (u16*)  (ws + 81920 + 48 * MB + 512 * 1024);
    u16*   wtz1   = (u16*)  (ws + 81920 + 49 * MB);          // 512x1024 bf16 = 1 MB
    float* bprime = (float*)(ws + 81920 + 50 * MB);          // 512 floats

    float* ypost  = buf0;
    float* z2f    = buf0;
    float* y      = buf1;
    u16*   a2_bf  = (u16*)buf1;
    u16*   emb_bf = (u16*)((char*)buf1 + 8 * MB);
    float* h      = buf2;
    u16*   z1_bf  = (u16*)buf2;

    focal_kernel<<<dim3(16), dim3(256), 0, stream>>>(cfl, out_focal);
    // static weight transposes (W2, Wh2, Wh1 abs-section) in one dispatch
    transpose3_kernel<<<dim3(16, 48), dim3(256), 0, stream>>>(W2, Wh2, Wh1, wte, wt2, wtz1);
    // tree recursions in projected 512-d space
    post_kernel<<<dim3(256), dim3(256), 0, stream>>>(ns, ch0, ch1, W1, c, ypost);
    pre_kernel<<<dim3(256), dim3(256), 0, stream>>>(par, c, ypost, y, flag2);
    // GCN layer 1: h = relu(agg(y) + b1), leaf/focal rows redirected to W1
    gcn_agg_kernel<1, 1, 0, 1><<<dim3(NROWS), dim3(128), 0, stream>>>(y, neigh, b1, ns, cfl,
                                                                      W1, h, nullptr);
    // GCN layer 2 aggregation: a2_bf = bf16(agg(h))
    gcn_agg_kernel<0, 0, 1, 0><<<dim3(NROWS), dim3(128), 0, stream>>>(h, neigh, b1, ns, cfl,
                                                                      W1, nullptr, a2_bf);
    // emb = a2 @ W2 + b2 -> out_emb (fp32) + emb_bf
    gemm_v5<0, 0><<<dim3(4, 128), dim3(256), 0, stream>>>(a2_bf, wte, b2, nullptr, nullptr,
                                                          nullptr, nullptr, out_emb, emb_bf,
                                                          NROWS, HID);
    // ef rows -> output
    ef_kernel<<<dim3(NNODES), dim3(256), 0, stream>>>(out_emb, bc, tv, isr, out_ef);
    // fold hf into z1 weights/bias (needs emb row FOCALR)
    zprep_kernel<<<dim3(16, 16), dim3(256), 0, stream>>>(Wh1, out_emb, wtz1);
    bvec_kernel<<<dim3(2), dim3(256), 0, stream>>>(Wh1, bh1, out_emb, bprime);
    // z1 = elu([ht | |hf-ht|] @ WTz1 + bprime + tv*t0 + isr*t1), K=1024
    gemm_v5<2, 1><<<dim3(4, 128), dim3(256), 0, stream>>>(emb_bf, wtz1, bprime, bc, tv, isr,
                                                          Wh1 + (long)2048 * HID, nullptr,
                                                          z1_bf, NNODES, 1024);
    // z2 = elu(z1 @ Wh2 + bh2) -> fp32
    gemm_v5<2, 0><<<dim3(4, 128), dim3(256), 0, stream>>>(z1_bf, wt2, bh2, nullptr, nullptr,
                                                          nullptr, nullptr, z2f, nullptr,
                                                          NNODES, HID);
    logits_kernel<<<dim3(2048), dim3(256), 0, stream>>>(z2f, Wh3, bh3, out_logits);
    softmax_kernel<<<dim3(1), dim3(1024), 0, stream>>>(out_logits, out_probs);
}